// Round 9
// baseline (224.735 us; speedup 1.0000x reference)
//
#include <hip/hip_runtime.h>
#include <hip/hip_bf16.h>

#define B_ 4
#define T_ 3
#define M_ 4096
#define C_ 768
#define H_ 12
#define K_ 256
#define HD_ 64
#define TM_ 4099      // T_ + M_
#define SCALE_ 0.125f // HD^-0.5
#define NBLK_ 144     // B*H*T, blk = b*36 + h*3 + t, j = h*3+t

typedef __attribute__((ext_vector_type(8))) short bf16x8;
typedef __attribute__((ext_vector_type(4))) float f32x4;

// order-preserving float->uint key (larger float -> larger key)
__device__ __forceinline__ unsigned keyf(float f) {
  unsigned u = __float_as_uint(f);
  return (u & 0x80000000u) ? ~u : (u | 0x80000000u);
}

__device__ __forceinline__ unsigned short f2bf(float f) { // RNE
  unsigned u = __float_as_uint(f);
  unsigned r = (u + 0x7FFFu + ((u >> 16) & 1u)) >> 16;
  return (unsigned short)r;
}
__device__ __forceinline__ unsigned pk2(float a, float b) {
  return (unsigned)f2bf(a) | ((unsigned)f2bf(b) << 16);
}

__device__ __forceinline__ int block_excl_scan256(int v, int tid, int* sbuf) {
  sbuf[tid] = v;
  __syncthreads();
  #pragma unroll
  for (int off = 1; off < 256; off <<= 1) {
    int add = (tid >= off) ? sbuf[tid - off] : 0;
    __syncthreads();
    sbuf[tid] += add;
    __syncthreads();
  }
  int inc = sbuf[tid];
  __syncthreads();
  return inc - v;
}

// ---------- kernels ----------
__global__ void zero_out_kernel(float4* __restrict__ out, int n4) {
  int i = blockIdx.x * 256 + threadIdx.x;
  if (i < n4) out[i] = make_float4(0.f, 0.f, 0.f, 0.f);
}

// q[b,t,d] = sum_c x[b,t,c] * Wq[t,d,c] + bq[t,d]
// grid = (T, 12 dchunks of 64), block = 256. Reads Wq once (4 b per block).
__global__ __launch_bounds__(256) void q_kernel(const float* __restrict__ x,
                                                const float* __restrict__ Wq,
                                                const float* __restrict__ bq,
                                                float* __restrict__ qbuf) {
  int t = blockIdx.x;
  int d0 = blockIdx.y * 64;
  int tid = threadIdx.x;
  __shared__ float ar[B_][C_];
  for (int i = tid; i < B_ * C_; i += 256) {
    int bb = i / C_, c = i % C_;
    ar[bb][c] = x[((size_t)(bb * TM_ + t)) * C_ + c];
  }
  __syncthreads();
  int grp = tid >> 4, ln = tid & 15;
  #pragma unroll
  for (int j = 0; j < 4; ++j) {
    int d = d0 + grp * 4 + j;
    const float4* wr = (const float4*)(Wq + ((size_t)t * C_ + d) * C_);
    float a0 = 0.f, a1 = 0.f, a2 = 0.f, a3 = 0.f;
    #pragma unroll
    for (int it = 0; it < 12; ++it) {
      float4 w4 = wr[ln + 16 * it];
      const float4 x0 = *(const float4*)&ar[0][(ln + 16 * it) * 4];
      const float4 x1 = *(const float4*)&ar[1][(ln + 16 * it) * 4];
      const float4 x2 = *(const float4*)&ar[2][(ln + 16 * it) * 4];
      const float4 x3 = *(const float4*)&ar[3][(ln + 16 * it) * 4];
      a0 += w4.x * x0.x + w4.y * x0.y + w4.z * x0.z + w4.w * x0.w;
      a1 += w4.x * x1.x + w4.y * x1.y + w4.z * x1.z + w4.w * x1.w;
      a2 += w4.x * x2.x + w4.y * x2.y + w4.z * x2.z + w4.w * x2.w;
      a3 += w4.x * x3.x + w4.y * x3.y + w4.z * x3.z + w4.w * x3.w;
    }
    #pragma unroll
    for (int off = 1; off < 16; off <<= 1) {
      a0 += __shfl_xor(a0, off, 16);
      a1 += __shfl_xor(a1, off, 16);
      a2 += __shfl_xor(a2, off, 16);
      a3 += __shfl_xor(a3, off, 16);
    }
    if (ln == 0) {
      float bqv = bq[t * C_ + d];
      qbuf[(size_t)(0 * T_ + t) * C_ + d] = a0 + bqv;
      qbuf[(size_t)(1 * T_ + t) * C_ + d] = a1 + bqv;
      qbuf[(size_t)(2 * T_ + t) * C_ + d] = a2 + bqv;
      qbuf[(size_t)(3 * T_ + t) * C_ + d] = a3 + bqv;
    }
  }
}

// sprjT[(b*768+c)*36 + j] = sum_{i<64} q[b,t,h*64+i] * Wkv[h*64+i, c]
// qbb[blk] = sum_{i<64} q[b,t,h*64+i] * bkv[h*64+i]
__global__ __launch_bounds__(256) void sprj_kernel(const float* __restrict__ qbuf,
                                                   const float* __restrict__ Wkv,
                                                   const float* __restrict__ bkv,
                                                   float* __restrict__ sprjT,
                                                   float* __restrict__ qbb) {
  int blk = blockIdx.x;
  int j = blk % 36;
  int b = blk / 36;
  int t = j % T_;
  int h = j / T_;
  int tid = threadIdx.x;
  __shared__ float qs[HD_];
  if (tid < HD_) qs[tid] = qbuf[((size_t)(b * T_ + t)) * C_ + h * HD_ + tid];
  __syncthreads();
  if (tid == 0) {
    float s = 0.f;
    for (int i = 0; i < HD_; ++i) s += qs[i] * bkv[h * HD_ + i];
    qbb[blk] = s;
  }
  float a0 = 0.f, a1 = 0.f, a2 = 0.f;
  for (int i = 0; i < HD_; ++i) {
    const float* wr = Wkv + ((size_t)(h * HD_ + i)) * C_;
    float qi = qs[i];
    a0 += qi * wr[tid];
    a1 += qi * wr[tid + 256];
    a2 += qi * wr[tid + 512];
  }
  sprjT[((size_t)b * C_ + tid) * 36 + j] = a0;
  sprjT[((size_t)b * C_ + tid + 256) * 36 + j] = a1;
  sprjT[((size_t)b * C_ + tid + 512) * 36 + j] = a2;
}

// score partials: scp[(cc*144 + b*36 + j)*M + m] = partial dot over 192 c's.
// grid = (B, 16 m-tiles of 256, 4 c-chunks), block = 256 (thread = one m).
__global__ __launch_bounds__(256) void score_kernel(const float* __restrict__ x,
                                                    const float* __restrict__ sprjT,
                                                    float* __restrict__ scp) {
  int b = blockIdx.x;
  int m0 = blockIdx.y * 256;
  int cc = blockIdx.z;
  int tid = threadIdx.x;

  __shared__ float fl[32][256]; // [c][m]

  float acc[36];
  #pragma unroll
  for (int j = 0; j < 36; ++j) acc[j] = 0.f;

  const float* fr0 = x + ((size_t)(b * TM_ + T_ + m0 + tid)) * C_ + cc * 192;

  for (int kc = 0; kc < 6; ++kc) {
    float4 v[8];
    const float4* fr = (const float4*)(fr0 + kc * 32);
    #pragma unroll
    for (int i = 0; i < 8; ++i) v[i] = fr[i];
    __syncthreads();
    #pragma unroll
    for (int i = 0; i < 8; ++i) {
      fl[i * 4 + 0][tid] = v[i].x;
      fl[i * 4 + 1][tid] = v[i].y;
      fl[i * 4 + 2][tid] = v[i].z;
      fl[i * 4 + 3][tid] = v[i].w;
    }
    __syncthreads();
    const float* sp = sprjT + ((size_t)b * C_ + cc * 192 + kc * 32) * 36;
    #pragma unroll 4
    for (int k = 0; k < 32; ++k) {
      float f = fl[k][tid];
      const float* sr = sp + k * 36; // uniform -> s_load
      #pragma unroll
      for (int j = 0; j < 36; ++j) acc[j] += f * sr[j];
    }
  }
  float* op = scp + ((size_t)cc * NBLK_ + (size_t)b * 36) * M_ + m0 + tid;
  #pragma unroll
  for (int j = 0; j < 36; ++j) op[(size_t)j * M_] = acc[j];
}

// scg[blk][m] = (sum_cc scp + qbb[blk]) * SCALE. grid = (144, 4), block 256.
__global__ __launch_bounds__(256) void score_reduce(const float* __restrict__ scp,
                                                    const float* __restrict__ qbb,
                                                    float* __restrict__ scg) {
  int blk = blockIdx.x;
  int m = blockIdx.y * 1024 + threadIdx.x * 4;
  float qb = qbb[blk];
  float4 a0 = *(const float4*)&scp[((size_t)0 * NBLK_ + blk) * M_ + m];
  float4 a1 = *(const float4*)&scp[((size_t)1 * NBLK_ + blk) * M_ + m];
  float4 a2 = *(const float4*)&scp[((size_t)2 * NBLK_ + blk) * M_ + m];
  float4 a3 = *(const float4*)&scp[((size_t)3 * NBLK_ + blk) * M_ + m];
  float4 o;
  o.x = (a0.x + a1.x + a2.x + a3.x + qb) * SCALE_;
  o.y = (a0.y + a1.y + a2.y + a3.y + qb) * SCALE_;
  o.z = (a0.z + a1.z + a2.z + a3.z + qb) * SCALE_;
  o.w = (a0.w + a1.w + a2.w + a3.w + qb) * SCALE_;
  *(float4*)&scg[(size_t)blk * M_ + m] = o;
}

// Per blk: exact top-K via radix select (index-ordered ties, = lax.top_k),
// softmax over selected; writes ibuf/wbuf. grid = 144, block = 256.
__global__ __launch_bounds__(256) void topk_kernel(const float* __restrict__ scg,
                                                   int* __restrict__ ibuf,
                                                   float* __restrict__ wbuf) {
  int blk = blockIdx.x;
  int tid = threadIdx.x;

  __shared__ float sc[M_];
  __shared__ unsigned hist[256];
  __shared__ int sbuf[256];
  __shared__ int selm[K_];
  __shared__ float red[256];
  __shared__ int sh_bin, sh_rem;

  const float4* srow = (const float4*)(scg + (size_t)blk * M_);
  for (int i = tid; i < M_ / 4; i += 256) ((float4*)sc)[i] = srow[i];
  __syncthreads();

  // ---- radix select: find K-th largest key ----
  unsigned prefix = 0;
  int remaining = K_;
  for (int shift = 24; shift >= 0; shift -= 8) {
    hist[tid] = 0;
    __syncthreads();
    unsigned pmask = (shift == 24) ? 0u : (0xFFFFFFFFu << (shift + 8));
    #pragma unroll 4
    for (int i = 0; i < 16; ++i) {
      unsigned k = keyf(sc[tid * 16 + i]);
      if ((k & pmask) == prefix) atomicAdd(&hist[(k >> shift) & 255u], 1u);
    }
    __syncthreads();
    int bin = 255 - tid;
    int v = (int)hist[bin];
    int cex = block_excl_scan256(v, tid, sbuf);
    if (cex < remaining && cex + v >= remaining) {
      sh_bin = bin;
      sh_rem = remaining - cex;
    }
    __syncthreads();
    prefix |= ((unsigned)sh_bin) << shift;
    remaining = sh_rem;
    __syncthreads();
  }
  const unsigned tau = prefix;
  const int r = remaining;      // # of ==tau entries to keep (lowest indices)
  const int cgt = K_ - r;       // # of >tau entries

  // ---- compact selection in ascending-index order (deterministic) ----
  int base = tid * 16;
  int myCnt = 0, myTie = 0;
  #pragma unroll
  for (int i = 0; i < 16; i++) {
    unsigned k = keyf(sc[base + i]);
    myCnt += (k > tau);
    myTie += (k == tau);
  }
  int offs = block_excl_scan256(myCnt, tid, sbuf);
  int toffs = block_excl_scan256(myTie, tid, sbuf);
  for (int i = 0; i < 16; i++) {
    int m = base + i;
    unsigned k = keyf(sc[m]);
    if (k > tau) {
      selm[offs++] = m;
    } else if (k == tau) {
      if (toffs < r) selm[cgt + toffs] = m;
      toffs++;
    }
  }
  __syncthreads();

  // ---- softmax over the K selected ----
  int m = selm[tid];
  float val = sc[m];
  red[tid] = val;
  __syncthreads();
  for (int off = 128; off > 0; off >>= 1) {
    if (tid < off) red[tid] = fmaxf(red[tid], red[tid + off]);
    __syncthreads();
  }
  float mx = red[0];
  __syncthreads();
  float e = expf(val - mx);
  red[tid] = e;
  __syncthreads();
  for (int off = 128; off > 0; off >>= 1) {
    if (tid < off) red[tid] += red[tid + off];
    __syncthreads();
  }
  ibuf[(size_t)blk * K_ + tid] = m;
  wbuf[(size_t)blk * K_ + tid] = e / red[0];
}

// wfp[blk*4+kc][c] = sum_{k in chunk} w_k * feat[m_k, c]
// grid = (144, 4, 3 c-segments), block = 256
__global__ __launch_bounds__(256) void wfeat_kernel(const float* __restrict__ x,
                                                    const int* __restrict__ ibuf,
                                                    const float* __restrict__ wbuf,
                                                    float* __restrict__ wfp) {
  int blk = blockIdx.x, kc = blockIdx.y, cseg = blockIdx.z;
  int b = blk / 36;
  int tid = threadIdx.x;
  __shared__ int ml[64];
  __shared__ float wl[64];
  if (tid < 64) {
    ml[tid] = ibuf[(size_t)blk * K_ + kc * 64 + tid];
    wl[tid] = wbuf[(size_t)blk * K_ + kc * 64 + tid];
  }
  __syncthreads();
  int c = cseg * 256 + tid;
  const float* fbase = x + ((size_t)b * TM_ + T_) * C_ + c;
  float a = 0.f;
  #pragma unroll 4
  for (int kk = 0; kk < 64; ++kk) {
    a += wl[kk] * fbase[(size_t)ml[kk] * C_];
  }
  wfp[((size_t)blk * 4 + kc) * C_ + c] = a;
}

// attn_token[b,t,h*64+rr] = (sum_kc wfp) . Wv[row] + bv[row]; grid = 144
__global__ __launch_bounds__(256) void attn_token_kernel(
    const float* __restrict__ wfp, const float* __restrict__ Wkv,
    const float* __restrict__ bkv, float* __restrict__ atbuf) {
  int blk = blockIdx.x;
  int t = blk % T_;
  int h = (blk / T_) % H_;
  int b = blk / (T_ * H_);
  int tid = threadIdx.x;
  __shared__ float wfeat[C_];
  const float* p0 = wfp + ((size_t)blk * 4) * C_;
  #pragma unroll
  for (int j = 0; j < 3; ++j) {
    int c = tid + j * 256;
    wfeat[c] = p0[c] + p0[C_ + c] + p0[2 * C_ + c] + p0[3 * C_ + c];
  }
  __syncthreads();
  int grp = tid >> 4, ln = tid & 15;
  for (int rr = grp; rr < HD_; rr += 16) {
    const float4* wr = (const float4*)(Wkv + ((size_t)(C_ + h * HD_ + rr)) * C_);
    float acc = 0.f;
    #pragma unroll
    for (int it = 0; it < 12; ++it) {
      float4 wv = wr[ln + it * 16];
      const float4 fv = *(const float4*)&wfeat[(ln + it * 16) * 4];
      acc += wv.x * fv.x + wv.y * fv.y + wv.z * fv.z + wv.w * fv.w;
    }
    acc += __shfl_xor(acc, 1, 16);
    acc += __shfl_xor(acc, 2, 16);
    acc += __shfl_xor(acc, 4, 16);
    acc += __shfl_xor(acc, 8, 16);
    if (ln == 0)
      atbuf[((size_t)(b * T_ + t)) * C_ + h * HD_ + rr] =
          acc + bkv[C_ + h * HD_ + rr];
  }
}

// token_output[b,t,d] = sum_c attn_token[b,t,c] * Wexp[t,d,c]
// grid = (T, 12 dchunks of 64), block 256. Reads Wexp once (4 b per block).
__global__ __launch_bounds__(256) void token_out(const float* __restrict__ atbuf,
                                                 const float* __restrict__ Wexp,
                                                 float* __restrict__ out) {
  int t = blockIdx.x;
  int d0 = blockIdx.y * 64;
  int tid = threadIdx.x;
  __shared__ float ar[B_][C_];
  for (int i = tid; i < B_ * C_; i += 256) {
    int bb = i / C_, c = i % C_;
    ar[bb][c] = atbuf[((size_t)(bb * T_ + t)) * C_ + c];
  }
  __syncthreads();
  int grp = tid >> 4, ln = tid & 15;
  #pragma unroll
  for (int j = 0; j < 4; ++j) {
    int d = d0 + grp * 4 + j;
    const float4* wr = (const float4*)(Wexp + ((size_t)t * C_ + d) * C_);
    float a0 = 0.f, a1 = 0.f, a2 = 0.f, a3 = 0.f;
    #pragma unroll
    for (int it = 0; it < 12; ++it) {
      float4 w4 = wr[ln + 16 * it];
      const float4 x0 = *(const float4*)&ar[0][(ln + 16 * it) * 4];
      const float4 x1 = *(const float4*)&ar[1][(ln + 16 * it) * 4];
      const float4 x2 = *(const float4*)&ar[2][(ln + 16 * it) * 4];
      const float4 x3 = *(const float4*)&ar[3][(ln + 16 * it) * 4];
      a0 += w4.x * x0.x + w4.y * x0.y + w4.z * x0.z + w4.w * x0.w;
      a1 += w4.x * x1.x + w4.y * x1.y + w4.z * x1.z + w4.w * x1.w;
      a2 += w4.x * x2.x + w4.y * x2.y + w4.z * x2.z + w4.w * x2.w;
      a3 += w4.x * x3.x + w4.y * x3.y + w4.z * x3.z + w4.w * x3.w;
    }
    #pragma unroll
    for (int off = 1; off < 16; off <<= 1) {
      a0 += __shfl_xor(a0, off, 16);
      a1 += __shfl_xor(a1, off, 16);
      a2 += __shfl_xor(a2, off, 16);
      a3 += __shfl_xor(a3, off, 16);
    }
    if (ln == 0) {
      out[((size_t)0 * TM_ + t) * C_ + d] = a0;
      out[((size_t)1 * TM_ + t) * C_ + d] = a1;
      out[((size_t)2 * TM_ + t) * C_ + d] = a2;
      out[((size_t)3 * TM_ + t) * C_ + d] = a3;
    }
  }
}

// Sparse feature expansion via MFMA GEMM per (t,h):
//   Y[64 rows][768 d] = FW[64x64 c] @ WexpT[64 c x 768 d], rows = (ks-chunk of
//   selections), then atomic-add rows into out[b, T+m, :].
// grid = (36 th, 16 rowtiles: b*4+ks), block = 256 (4 waves).
// LDS: fw bf16 [64][72] + wt bf16 [192][72] (+pad: 2-way reads = free).
__global__ __launch_bounds__(256) void scatter_mfma(
    const float* __restrict__ x, const float* __restrict__ Wexp,
    const int* __restrict__ ibuf, const float* __restrict__ wbuf,
    float* __restrict__ out) {
  int th = blockIdx.x;
  int h = th / T_, t = th % T_;
  int rt = blockIdx.y;
  int b = rt >> 2, ks = rt & 3;
  int bht = b * 36 + th;
  int tid = threadIdx.x;

  __shared__ unsigned short fw[64][72];
  __shared__ unsigned short wt[192][72];
  __shared__ int ml[64];

  if (tid < 64) ml[tid] = ibuf[(size_t)bht * K_ + ks * 64 + tid];
  // stage fw (bf16 of w * feat slice): thread = (kk, 16-c chunk)
  {
    int kk = tid >> 2, cp = (tid & 3) * 16;
    int sel = ks * 64 + kk;
    int m = ibuf[(size_t)bht * K_ + sel];
    float w = wbuf[(size_t)bht * K_ + sel];
    const float* fr = x + ((size_t)(b * TM_) + T_ + m) * C_ + h * HD_ + cp;
    float4 f0 = *(const float4*)(fr + 0);
    float4 f1 = *(const float4*)(fr + 4);
    float4 f2 = *(const float4*)(fr + 8);
    float4 f3 = *(const float4*)(fr + 12);
    uint4 u0 = make_uint4(pk2(f0.x * w, f0.y * w), pk2(f0.z * w, f0.w * w),
                          pk2(f1.x * w, f1.y * w), pk2(f1.z * w, f1.w * w));
    uint4 u1 = make_uint4(pk2(f2.x * w, f2.y * w), pk2(f2.z * w, f2.w * w),
                          pk2(f3.x * w, f3.y * w), pk2(f3.z * w, f3.w * w));
    *(uint4*)&fw[kk][cp] = u0;
    *(uint4*)&fw[kk][cp + 8] = u1;
  }
  __syncthreads();

  int lane = tid & 63, wave = tid >> 6;
  int lrow = lane & 15, lk8 = (lane >> 4) * 8, g4 = (lane >> 4) * 4;

  for (int dc = 0; dc < 4; ++dc) {
    // stage wt[dd][c] = bf16(Wexp[t, dc*192+dd, h*64+c]) — coalesced rows
    {
      #pragma unroll
      for (int r2 = 0; r2 < 3; ++r2) {
        int idx = r2 * 256 + tid;
        int dd = idx >> 2, cq = (idx & 3) * 16;
        const float* wr =
            Wexp + ((size_t)t * C_ + dc * 192 + dd) * C_ + h * HD_ + cq;
        float4 f0 = *(const float4*)(wr + 0);
        float4 f1 = *(const float4*)(wr + 4);
        float4 f2 = *(const float4*)(wr + 8);
        float4 f3 = *(const float4*)(wr + 12);
        uint4 u0 = make_uint4(pk2(f0.x, f0.y), pk2(f0.z, f0.w),
                              pk2(f1.x, f1.y), pk2(f1.z, f1.w));
        uint4 u1 = make_uint4(pk2(f2.x, f2.y), pk2(f2.z, f2.w),
                              pk2(f3.x, f3.y), pk2(f3.z, f3.w));
        *(uint4*)&wt[dd][cq] = u0;
        *(uint4*)&wt[dd][cq + 8] = u1;
      }
    }
    __syncthreads();

    f32x4 acc[12];
    #pragma unroll
    for (int n = 0; n < 12; ++n) acc[n] = (f32x4){0.f, 0.f, 0.f, 0.f};

    #pragma unroll
    for (int ks2 = 0; ks2 < 2; ++ks2) {
      bf16x8 a = *(const bf16x8*)&fw[wave * 16 + lrow][ks2 * 32 + lk8];
      #pragma unroll
      for (int n = 0; n < 12; ++n) {
        bf16x8 bfr = *(const bf16x8*)&wt[n * 16 + lrow][ks2 * 32 + lk8];
        acc[n] = __builtin_amdgcn_mfma_f32_16x16x32_bf16(a, bfr, acc[n], 0, 0, 0);
      }
    }

    // epilogue: D col = lane&15 (d), row = (lane>>4)*4 + q (local row)
    #pragma unroll
    for (int n = 0; n < 12; ++n) {
      int d = dc * 192 + n * 16 + lrow;
      #pragma unroll
      for (int q = 0; q < 4; ++q) {
        int row = wave * 16 + g4 + q;
        int mrow = ml[row];
        atomicAdd(&out[((size_t)b * TM_ + T_ + mrow) * C_ + d], acc[n][q]);
      }
    }
    __syncthreads(); // all reads of wt done before next-dc overwrite
  }
}

// ---------- launch ----------
extern "C" void kernel_launch(void* const* d_in, const int* in_sizes, int n_in,
                              void* d_out, int out_size, void* d_ws, size_t ws_size,
                              hipStream_t stream) {
  (void)in_sizes; (void)n_in; (void)ws_size;
  const float* x = (const float*)d_in[0];
  const float* Wq = (const float*)d_in[1];
  const float* bq = (const float*)d_in[2];
  const float* Wkv = (const float*)d_in[3];
  const float* bkv = (const float*)d_in[4];
  const float* Wexp = (const float*)d_in[5];
  float* out = (float*)d_out;

  // workspace layout (~14.4 MiB used)
  char* ws = (char*)d_ws;
  float* qbuf = (float*)ws;                          //        36,864 B
  float* atbuf = (float*)(ws + 36864);               //        36,864 B
  int* ibuf = (int*)(ws + 73728);                    //       147,456 B
  float* wbuf = (float*)(ws + 221184);               //       147,456 B
  float* sprjT = (float*)(ws + 368640);              //       442,368 B
  float* qbb = (float*)(ws + 811008);                //     1,024 B pad
  float* scg = (float*)(ws + 812032);                //     2,359,296 B
  float* scp = (float*)(ws + 3171328);               //     9,437,184 B
  float* wfp = (float*)(ws + 12608512);              //     1,769,472 B

  int n4 = out_size / 4;
  zero_out_kernel<<<(n4 + 255) / 256, 256, 0, stream>>>((float4*)out, n4);
  q_kernel<<<dim3(T_, 12), 256, 0, stream>>>(x, Wq, bq, qbuf);
  sprj_kernel<<<NBLK_, 256, 0, stream>>>(qbuf, Wkv, bkv, sprjT, qbb);
  score_kernel<<<dim3(B_, 16, 4), 256, 0, stream>>>(x, sprjT, scp);
  score_reduce<<<dim3(NBLK_, 4), 256, 0, stream>>>(scp, qbb, scg);
  topk_kernel<<<NBLK_, 256, 0, stream>>>(scg, ibuf, wbuf);
  wfeat_kernel<<<dim3(NBLK_, 4, 3), 256, 0, stream>>>(x, ibuf, wbuf, wfp);
  attn_token_kernel<<<NBLK_, 256, 0, stream>>>(wfp, Wkv, bkv, atbuf);
  token_out<<<dim3(T_, 12), 256, 0, stream>>>(atbuf, Wexp, out);
  scatter_mfma<<<dim3(36, 16), 256, 0, stream>>>(x, Wexp, ibuf, wbuf, out);
}

// Round 10
// 202.730 us; speedup vs baseline: 1.1085x; 1.1085x over previous
//
#include <hip/hip_runtime.h>
#include <hip/hip_bf16.h>

#define B_ 4
#define T_ 3
#define M_ 4096
#define C_ 768
#define H_ 12
#define K_ 256
#define HD_ 64
#define TM_ 4099      // T_ + M_
#define SCALE_ 0.125f // HD^-0.5
#define NBLK_ 144     // B*H*T, blk = b*36 + h*3 + t, th = h*3+t

typedef __attribute__((ext_vector_type(8))) short bf16x8;
typedef __attribute__((ext_vector_type(4))) float f32x4;

// order-preserving float->uint key (larger float -> larger key)
__device__ __forceinline__ unsigned keyf(float f) {
  unsigned u = __float_as_uint(f);
  return (u & 0x80000000u) ? ~u : (u | 0x80000000u);
}

__device__ __forceinline__ unsigned short f2bf(float f) { // RNE
  unsigned u = __float_as_uint(f);
  unsigned r = (u + 0x7FFFu + ((u >> 16) & 1u)) >> 16;
  return (unsigned short)r;
}
__device__ __forceinline__ unsigned pk2(float a, float b) {
  return (unsigned)f2bf(a) | ((unsigned)f2bf(b) << 16);
}

__device__ __forceinline__ int block_excl_scan256(int v, int tid, int* sbuf) {
  sbuf[tid] = v;
  __syncthreads();
  #pragma unroll
  for (int off = 1; off < 256; off <<= 1) {
    int add = (tid >= off) ? sbuf[tid - off] : 0;
    __syncthreads();
    sbuf[tid] += add;
    __syncthreads();
  }
  int inc = sbuf[tid];
  __syncthreads();
  return inc - v;
}

// ---------- kernels ----------

// q[b,t,d] = sum_c x[b,t,c] * Wq[t,d,c] + bq[t,d]
// grid = (T, 12 dchunks of 64), block = 256. Reads Wq once (4 b per block).
__global__ __launch_bounds__(256) void q_kernel(const float* __restrict__ x,
                                                const float* __restrict__ Wq,
                                                const float* __restrict__ bq,
                                                float* __restrict__ qbuf) {
  int t = blockIdx.x;
  int d0 = blockIdx.y * 64;
  int tid = threadIdx.x;
  __shared__ float ar[B_][C_];
  for (int i = tid; i < B_ * C_; i += 256) {
    int bb = i / C_, c = i % C_;
    ar[bb][c] = x[((size_t)(bb * TM_ + t)) * C_ + c];
  }
  __syncthreads();
  int grp = tid >> 4, ln = tid & 15;
  #pragma unroll
  for (int j = 0; j < 4; ++j) {
    int d = d0 + grp * 4 + j;
    const float4* wr = (const float4*)(Wq + ((size_t)t * C_ + d) * C_);
    float a0 = 0.f, a1 = 0.f, a2 = 0.f, a3 = 0.f;
    #pragma unroll
    for (int it = 0; it < 12; ++it) {
      float4 w4 = wr[ln + 16 * it];
      const float4 x0 = *(const float4*)&ar[0][(ln + 16 * it) * 4];
      const float4 x1 = *(const float4*)&ar[1][(ln + 16 * it) * 4];
      const float4 x2 = *(const float4*)&ar[2][(ln + 16 * it) * 4];
      const float4 x3 = *(const float4*)&ar[3][(ln + 16 * it) * 4];
      a0 += w4.x * x0.x + w4.y * x0.y + w4.z * x0.z + w4.w * x0.w;
      a1 += w4.x * x1.x + w4.y * x1.y + w4.z * x1.z + w4.w * x1.w;
      a2 += w4.x * x2.x + w4.y * x2.y + w4.z * x2.z + w4.w * x2.w;
      a3 += w4.x * x3.x + w4.y * x3.y + w4.z * x3.z + w4.w * x3.w;
    }
    #pragma unroll
    for (int off = 1; off < 16; off <<= 1) {
      a0 += __shfl_xor(a0, off, 16);
      a1 += __shfl_xor(a1, off, 16);
      a2 += __shfl_xor(a2, off, 16);
      a3 += __shfl_xor(a3, off, 16);
    }
    if (ln == 0) {
      float bqv = bq[t * C_ + d];
      qbuf[(size_t)(0 * T_ + t) * C_ + d] = a0 + bqv;
      qbuf[(size_t)(1 * T_ + t) * C_ + d] = a1 + bqv;
      qbuf[(size_t)(2 * T_ + t) * C_ + d] = a2 + bqv;
      qbuf[(size_t)(3 * T_ + t) * C_ + d] = a3 + bqv;
    }
  }
}

// sprjT[(b*768+c)*36 + j] = sum_{i<64} q[b,t,h*64+i] * Wkv[h*64+i, c]
// qbb[blk] = sum_{i<64} q[b,t,h*64+i] * bkv[h*64+i]
__global__ __launch_bounds__(256) void sprj_kernel(const float* __restrict__ qbuf,
                                                   const float* __restrict__ Wkv,
                                                   const float* __restrict__ bkv,
                                                   float* __restrict__ sprjT,
                                                   float* __restrict__ qbb) {
  int blk = blockIdx.x;
  int j = blk % 36;
  int b = blk / 36;
  int t = j % T_;
  int h = j / T_;
  int tid = threadIdx.x;
  __shared__ float qs[HD_];
  if (tid < HD_) qs[tid] = qbuf[((size_t)(b * T_ + t)) * C_ + h * HD_ + tid];
  __syncthreads();
  if (tid == 0) {
    float s = 0.f;
    for (int i = 0; i < HD_; ++i) s += qs[i] * bkv[h * HD_ + i];
    qbb[blk] = s;
  }
  float a0 = 0.f, a1 = 0.f, a2 = 0.f;
  for (int i = 0; i < HD_; ++i) {
    const float* wr = Wkv + ((size_t)(h * HD_ + i)) * C_;
    float qi = qs[i];
    a0 += qi * wr[tid];
    a1 += qi * wr[tid + 256];
    a2 += qi * wr[tid + 512];
  }
  sprjT[((size_t)b * C_ + tid) * 36 + j] = a0;
  sprjT[((size_t)b * C_ + tid + 256) * 36 + j] = a1;
  sprjT[((size_t)b * C_ + tid + 512) * 36 + j] = a2;
}

// score partials: scp[(cc*144 + b*36 + j)*M + m] = partial dot over 192 c's.
// grid = (B, 16 m-tiles of 256, 4 c-chunks), block = 256 (thread = one m).
__global__ __launch_bounds__(256) void score_kernel(const float* __restrict__ x,
                                                    const float* __restrict__ sprjT,
                                                    float* __restrict__ scp) {
  int b = blockIdx.x;
  int m0 = blockIdx.y * 256;
  int cc = blockIdx.z;
  int tid = threadIdx.x;

  __shared__ float fl[32][256]; // [c][m]

  float acc[36];
  #pragma unroll
  for (int j = 0; j < 36; ++j) acc[j] = 0.f;

  const float* fr0 = x + ((size_t)(b * TM_ + T_ + m0 + tid)) * C_ + cc * 192;

  for (int kc = 0; kc < 6; ++kc) {
    float4 v[8];
    const float4* fr = (const float4*)(fr0 + kc * 32);
    #pragma unroll
    for (int i = 0; i < 8; ++i) v[i] = fr[i];
    __syncthreads();
    #pragma unroll
    for (int i = 0; i < 8; ++i) {
      fl[i * 4 + 0][tid] = v[i].x;
      fl[i * 4 + 1][tid] = v[i].y;
      fl[i * 4 + 2][tid] = v[i].z;
      fl[i * 4 + 3][tid] = v[i].w;
    }
    __syncthreads();
    const float* sp = sprjT + ((size_t)b * C_ + cc * 192 + kc * 32) * 36;
    #pragma unroll 4
    for (int k = 0; k < 32; ++k) {
      float f = fl[k][tid];
      const float* sr = sp + k * 36; // uniform -> s_load
      #pragma unroll
      for (int j = 0; j < 36; ++j) acc[j] += f * sr[j];
    }
  }
  float* op = scp + ((size_t)cc * NBLK_ + (size_t)b * 36) * M_ + m0 + tid;
  #pragma unroll
  for (int j = 0; j < 36; ++j) op[(size_t)j * M_] = acc[j];
}

// scg[blk][m] = (sum_cc scp + qbb[blk]) * SCALE. grid = (144, 4), block 256.
__global__ __launch_bounds__(256) void score_reduce(const float* __restrict__ scp,
                                                    const float* __restrict__ qbb,
                                                    float* __restrict__ scg) {
  int blk = blockIdx.x;
  int m = blockIdx.y * 1024 + threadIdx.x * 4;
  float qb = qbb[blk];
  float4 a0 = *(const float4*)&scp[((size_t)0 * NBLK_ + blk) * M_ + m];
  float4 a1 = *(const float4*)&scp[((size_t)1 * NBLK_ + blk) * M_ + m];
  float4 a2 = *(const float4*)&scp[((size_t)2 * NBLK_ + blk) * M_ + m];
  float4 a3 = *(const float4*)&scp[((size_t)3 * NBLK_ + blk) * M_ + m];
  float4 o;
  o.x = (a0.x + a1.x + a2.x + a3.x + qb) * SCALE_;
  o.y = (a0.y + a1.y + a2.y + a3.y + qb) * SCALE_;
  o.z = (a0.z + a1.z + a2.z + a3.z + qb) * SCALE_;
  o.w = (a0.w + a1.w + a2.w + a3.w + qb) * SCALE_;
  *(float4*)&scg[(size_t)blk * M_ + m] = o;
}

// Per blk: exact top-K via radix select (index-ordered ties, = lax.top_k),
// softmax over selected; writes ibuf/wbuf. grid = 144, block = 256.
__global__ __launch_bounds__(256) void topk_kernel(const float* __restrict__ scg,
                                                   int* __restrict__ ibuf,
                                                   float* __restrict__ wbuf) {
  int blk = blockIdx.x;
  int tid = threadIdx.x;

  __shared__ float sc[M_];
  __shared__ unsigned hist[256];
  __shared__ int sbuf[256];
  __shared__ int selm[K_];
  __shared__ float red[256];
  __shared__ int sh_bin, sh_rem;

  const float4* srow = (const float4*)(scg + (size_t)blk * M_);
  for (int i = tid; i < M_ / 4; i += 256) ((float4*)sc)[i] = srow[i];
  __syncthreads();

  // ---- radix select: find K-th largest key ----
  unsigned prefix = 0;
  int remaining = K_;
  for (int shift = 24; shift >= 0; shift -= 8) {
    hist[tid] = 0;
    __syncthreads();
    unsigned pmask = (shift == 24) ? 0u : (0xFFFFFFFFu << (shift + 8));
    #pragma unroll 4
    for (int i = 0; i < 16; ++i) {
      unsigned k = keyf(sc[tid * 16 + i]);
      if ((k & pmask) == prefix) atomicAdd(&hist[(k >> shift) & 255u], 1u);
    }
    __syncthreads();
    int bin = 255 - tid;
    int v = (int)hist[bin];
    int cex = block_excl_scan256(v, tid, sbuf);
    if (cex < remaining && cex + v >= remaining) {
      sh_bin = bin;
      sh_rem = remaining - cex;
    }
    __syncthreads();
    prefix |= ((unsigned)sh_bin) << shift;
    remaining = sh_rem;
    __syncthreads();
  }
  const unsigned tau = prefix;
  const int r = remaining;      // # of ==tau entries to keep (lowest indices)
  const int cgt = K_ - r;       // # of >tau entries

  // ---- compact selection in ascending-index order (deterministic) ----
  int base = tid * 16;
  int myCnt = 0, myTie = 0;
  #pragma unroll
  for (int i = 0; i < 16; i++) {
    unsigned k = keyf(sc[base + i]);
    myCnt += (k > tau);
    myTie += (k == tau);
  }
  int offs = block_excl_scan256(myCnt, tid, sbuf);
  int toffs = block_excl_scan256(myTie, tid, sbuf);
  for (int i = 0; i < 16; i++) {
    int m = base + i;
    unsigned k = keyf(sc[m]);
    if (k > tau) {
      selm[offs++] = m;
    } else if (k == tau) {
      if (toffs < r) selm[cgt + toffs] = m;
      toffs++;
    }
  }
  __syncthreads();

  // ---- softmax over the K selected ----
  int m = selm[tid];
  float val = sc[m];
  red[tid] = val;
  __syncthreads();
  for (int off = 128; off > 0; off >>= 1) {
    if (tid < off) red[tid] = fmaxf(red[tid], red[tid + off]);
    __syncthreads();
  }
  float mx = red[0];
  __syncthreads();
  float e = expf(val - mx);
  red[tid] = e;
  __syncthreads();
  for (int off = 128; off > 0; off >>= 1) {
    if (tid < off) red[tid] += red[tid + off];
    __syncthreads();
  }
  ibuf[(size_t)blk * K_ + tid] = m;
  wbuf[(size_t)blk * K_ + tid] = e / red[0];
}

// wfp[blk*4+kc][c] = sum_{k in chunk} w_k * feat[m_k, c]
// grid = (144, 4, 3 c-segments), block = 256
__global__ __launch_bounds__(256) void wfeat_kernel(const float* __restrict__ x,
                                                    const int* __restrict__ ibuf,
                                                    const float* __restrict__ wbuf,
                                                    float* __restrict__ wfp) {
  int blk = blockIdx.x, kc = blockIdx.y, cseg = blockIdx.z;
  int b = blk / 36;
  int tid = threadIdx.x;
  __shared__ int ml[64];
  __shared__ float wl[64];
  if (tid < 64) {
    ml[tid] = ibuf[(size_t)blk * K_ + kc * 64 + tid];
    wl[tid] = wbuf[(size_t)blk * K_ + kc * 64 + tid];
  }
  __syncthreads();
  int c = cseg * 256 + tid;
  const float* fbase = x + ((size_t)b * TM_ + T_) * C_ + c;
  float a = 0.f;
  #pragma unroll 4
  for (int kk = 0; kk < 64; ++kk) {
    a += wl[kk] * fbase[(size_t)ml[kk] * C_];
  }
  wfp[((size_t)blk * 4 + kc) * C_ + c] = a;
}

// attn_token[b,t,h*64+rr] = (sum_kc wfp) . Wv[row] + bv[row]; grid = 144
__global__ __launch_bounds__(256) void attn_token_kernel(
    const float* __restrict__ wfp, const float* __restrict__ Wkv,
    const float* __restrict__ bkv, float* __restrict__ atbuf) {
  int blk = blockIdx.x;
  int t = blk % T_;
  int h = (blk / T_) % H_;
  int b = blk / (T_ * H_);
  int tid = threadIdx.x;
  __shared__ float wfeat[C_];
  const float* p0 = wfp + ((size_t)blk * 4) * C_;
  #pragma unroll
  for (int j = 0; j < 3; ++j) {
    int c = tid + j * 256;
    wfeat[c] = p0[c] + p0[C_ + c] + p0[2 * C_ + c] + p0[3 * C_ + c];
  }
  __syncthreads();
  int grp = tid >> 4, ln = tid & 15;
  for (int rr = grp; rr < HD_; rr += 16) {
    const float4* wr = (const float4*)(Wkv + ((size_t)(C_ + h * HD_ + rr)) * C_);
    float acc = 0.f;
    #pragma unroll
    for (int it = 0; it < 12; ++it) {
      float4 wv = wr[ln + it * 16];
      const float4 fv = *(const float4*)&wfeat[(ln + it * 16) * 4];
      acc += wv.x * fv.x + wv.y * fv.y + wv.z * fv.z + wv.w * fv.w;
    }
    acc += __shfl_xor(acc, 1, 16);
    acc += __shfl_xor(acc, 2, 16);
    acc += __shfl_xor(acc, 4, 16);
    acc += __shfl_xor(acc, 8, 16);
    if (ln == 0)
      atbuf[((size_t)(b * T_ + t)) * C_ + h * HD_ + rr] =
          acc + bkv[C_ + h * HD_ + rr];
  }
}

// token_output[b,t,d] = sum_c attn_token[b,t,c] * Wexp[t,d,c]
// grid = (T, 12 dchunks of 64), block 256. Fully writes task rows of out.
__global__ __launch_bounds__(256) void token_out(const float* __restrict__ atbuf,
                                                 const float* __restrict__ Wexp,
                                                 float* __restrict__ out) {
  int t = blockIdx.x;
  int d0 = blockIdx.y * 64;
  int tid = threadIdx.x;
  __shared__ float ar[B_][C_];
  for (int i = tid; i < B_ * C_; i += 256) {
    int bb = i / C_, c = i % C_;
    ar[bb][c] = atbuf[((size_t)(bb * T_ + t)) * C_ + c];
  }
  __syncthreads();
  int grp = tid >> 4, ln = tid & 15;
  #pragma unroll
  for (int j = 0; j < 4; ++j) {
    int d = d0 + grp * 4 + j;
    const float4* wr = (const float4*)(Wexp + ((size_t)t * C_ + d) * C_);
    float a0 = 0.f, a1 = 0.f, a2 = 0.f, a3 = 0.f;
    #pragma unroll
    for (int it = 0; it < 12; ++it) {
      float4 w4 = wr[ln + 16 * it];
      const float4 x0 = *(const float4*)&ar[0][(ln + 16 * it) * 4];
      const float4 x1 = *(const float4*)&ar[1][(ln + 16 * it) * 4];
      const float4 x2 = *(const float4*)&ar[2][(ln + 16 * it) * 4];
      const float4 x3 = *(const float4*)&ar[3][(ln + 16 * it) * 4];
      a0 += w4.x * x0.x + w4.y * x0.y + w4.z * x0.z + w4.w * x0.w;
      a1 += w4.x * x1.x + w4.y * x1.y + w4.z * x1.z + w4.w * x1.w;
      a2 += w4.x * x2.x + w4.y * x2.y + w4.z * x2.z + w4.w * x2.w;
      a3 += w4.x * x3.x + w4.y * x3.y + w4.z * x3.z + w4.w * x3.w;
    }
    #pragma unroll
    for (int off = 1; off < 16; off <<= 1) {
      a0 += __shfl_xor(a0, off, 16);
      a1 += __shfl_xor(a1, off, 16);
      a2 += __shfl_xor(a2, off, 16);
      a3 += __shfl_xor(a3, off, 16);
    }
    if (ln == 0) {
      out[((size_t)0 * TM_ + t) * C_ + d] = a0;
      out[((size_t)1 * TM_ + t) * C_ + d] = a1;
      out[((size_t)2 * TM_ + t) * C_ + d] = a2;
      out[((size_t)3 * TM_ + t) * C_ + d] = a3;
    }
  }
}

// Inverted index: bucket[(b*M+m)*36 + th] = sel+1 (0 = none).
// Per (b,m) each th contributes at most one sel (top-k indices distinct) ->
// no atomics, fully deterministic. grid = 144, block = 256.
__global__ void bucket_build(const int* __restrict__ ibuf,
                             int* __restrict__ bucket) {
  int bht = blockIdx.x;
  int b = bht / 36, th = bht % 36;
  int sel = threadIdx.x;
  int m = ibuf[(size_t)bht * K_ + sel];
  bucket[((size_t)b * M_ + m) * 36 + th] = sel + 1;
}

// Per-b MFMA GEMM into dense Y (no atomics):
//   Y[th][sel][d] = w_sel * feat[b, m_sel, h64 block] @ Wexp[t,:,h64 block]^T
// grid = (36 th, 4 ks, 4 dc), block = 256 (4 waves).
__global__ __launch_bounds__(256) void scatter_mfma(
    const float* __restrict__ x, const float* __restrict__ Wexp,
    const int* __restrict__ ibuf, const float* __restrict__ wbuf,
    float* __restrict__ Y, int b) {
  int th = blockIdx.x;
  int h = th / T_, t = th % T_;
  int ks = blockIdx.y;
  int dc = blockIdx.z;
  int bht = b * 36 + th;
  int tid = threadIdx.x;

  __shared__ unsigned short fw[64][72];
  __shared__ unsigned short wt[192][72];

  // stage fw (bf16 of w * feat slice): thread = (kk, 16-c chunk)
  {
    int kk = tid >> 2, cp = (tid & 3) * 16;
    int sel = ks * 64 + kk;
    int m = ibuf[(size_t)bht * K_ + sel];
    float w = wbuf[(size_t)bht * K_ + sel];
    const float* fr = x + ((size_t)(b * TM_) + T_ + m) * C_ + h * HD_ + cp;
    float4 f0 = *(const float4*)(fr + 0);
    float4 f1 = *(const float4*)(fr + 4);
    float4 f2 = *(const float4*)(fr + 8);
    float4 f3 = *(const float4*)(fr + 12);
    uint4 u0 = make_uint4(pk2(f0.x * w, f0.y * w), pk2(f0.z * w, f0.w * w),
                          pk2(f1.x * w, f1.y * w), pk2(f1.z * w, f1.w * w));
    uint4 u1 = make_uint4(pk2(f2.x * w, f2.y * w), pk2(f2.z * w, f2.w * w),
                          pk2(f3.x * w, f3.y * w), pk2(f3.z * w, f3.w * w));
    *(uint4*)&fw[kk][cp] = u0;
    *(uint4*)&fw[kk][cp + 8] = u1;
  }
  // stage wt[dd][c] = bf16(Wexp[t, dc*192+dd, h*64+c]) — coalesced rows
  {
    #pragma unroll
    for (int r2 = 0; r2 < 3; ++r2) {
      int idx = r2 * 256 + tid;
      int dd = idx >> 2, cq = (idx & 3) * 16;
      const float* wr =
          Wexp + ((size_t)t * C_ + dc * 192 + dd) * C_ + h * HD_ + cq;
      float4 f0 = *(const float4*)(wr + 0);
      float4 f1 = *(const float4*)(wr + 4);
      float4 f2 = *(const float4*)(wr + 8);
      float4 f3 = *(const float4*)(wr + 12);
      uint4 u0 = make_uint4(pk2(f0.x, f0.y), pk2(f0.z, f0.w),
                            pk2(f1.x, f1.y), pk2(f1.z, f1.w));
      uint4 u1 = make_uint4(pk2(f2.x, f2.y), pk2(f2.z, f2.w),
                            pk2(f3.x, f3.y), pk2(f3.z, f3.w));
      *(uint4*)&wt[dd][cq] = u0;
      *(uint4*)&wt[dd][cq + 8] = u1;
    }
  }
  __syncthreads();

  int lane = tid & 63, wave = tid >> 6;
  int lrow = lane & 15, lk8 = (lane >> 4) * 8, g4 = (lane >> 4) * 4;

  f32x4 acc[12];
  #pragma unroll
  for (int n = 0; n < 12; ++n) acc[n] = (f32x4){0.f, 0.f, 0.f, 0.f};

  #pragma unroll
  for (int ks2 = 0; ks2 < 2; ++ks2) {
    bf16x8 a = *(const bf16x8*)&fw[wave * 16 + lrow][ks2 * 32 + lk8];
    #pragma unroll
    for (int n = 0; n < 12; ++n) {
      bf16x8 bfr = *(const bf16x8*)&wt[n * 16 + lrow][ks2 * 32 + lk8];
      acc[n] = __builtin_amdgcn_mfma_f32_16x16x32_bf16(a, bfr, acc[n], 0, 0, 0);
    }
  }

  // epilogue: D col = lane&15 (d), row = (lane>>4)*4 + q (local row).
  // Plain coalesced stores to Y — no atomics.
  #pragma unroll
  for (int n = 0; n < 12; ++n) {
    int d = dc * 192 + n * 16 + lrow;
    #pragma unroll
    for (int q = 0; q < 4; ++q) {
      int row = ks * 64 + wave * 16 + g4 + q;
      Y[((size_t)th * K_ + row) * C_ + d] = acc[n][q];
    }
  }
}

// Combine: out[b, T+m, :] = sum over active th (ascending, deterministic) of
// Y[th][sel][:]. Rows with no contributions get zeros (replaces zero_out).
// grid = M/4 blocks, block = 256 (wave per m row).
__global__ __launch_bounds__(256) void combine_kernel(
    const float* __restrict__ Y, const int* __restrict__ bucket,
    float* __restrict__ out, int b) {
  int wave = threadIdx.x >> 6, lane = threadIdx.x & 63;
  int m = blockIdx.x * 4 + wave;
  const int* bk = bucket + ((size_t)b * M_ + m) * 36;
  int v = (lane < 36) ? bk[lane] : 0;
  unsigned long long mask = __ballot(v > 0);
  float4 a0 = make_float4(0.f, 0.f, 0.f, 0.f);
  float4 a1 = make_float4(0.f, 0.f, 0.f, 0.f);
  float4 a2 = make_float4(0.f, 0.f, 0.f, 0.f);
  while (mask) {
    int th = __ffsll((unsigned long long)mask) - 1;
    mask &= mask - 1;
    int sel = __shfl(v, th) - 1;
    const float* yr = Y + ((size_t)th * K_ + sel) * C_;
    float4 r0 = *(const float4*)(yr + lane * 4);
    float4 r1 = *(const float4*)(yr + 256 + lane * 4);
    float4 r2 = *(const float4*)(yr + 512 + lane * 4);
    a0.x += r0.x; a0.y += r0.y; a0.z += r0.z; a0.w += r0.w;
    a1.x += r1.x; a1.y += r1.y; a1.z += r1.z; a1.w += r1.w;
    a2.x += r2.x; a2.y += r2.y; a2.z += r2.z; a2.w += r2.w;
  }
  float* orow = out + ((size_t)b * TM_ + T_ + m) * C_;
  *(float4*)(orow + lane * 4) = a0;
  *(float4*)(orow + 256 + lane * 4) = a1;
  *(float4*)(orow + 512 + lane * 4) = a2;
}

// ---------- launch ----------
extern "C" void kernel_launch(void* const* d_in, const int* in_sizes, int n_in,
                              void* d_out, int out_size, void* d_ws, size_t ws_size,
                              hipStream_t stream) {
  (void)in_sizes; (void)n_in; (void)ws_size; (void)out_size;
  const float* x = (const float*)d_in[0];
  const float* Wq = (const float*)d_in[1];
  const float* bq = (const float*)d_in[2];
  const float* Wkv = (const float*)d_in[3];
  const float* bkv = (const float*)d_in[4];
  const float* Wexp = (const float*)d_in[5];
  float* out = (float*)d_out;

  // workspace layout (~45.0 MiB total)
  char* ws = (char*)d_ws;
  float* qbuf = (float*)ws;                          //        36,864 B
  float* atbuf = (float*)(ws + 36864);               //        36,864 B
  int* ibuf = (int*)(ws + 73728);                    //       147,456 B
  float* wbuf = (float*)(ws + 221184);               //       147,456 B
  float* sprjT = (float*)(ws + 368640);              //       442,368 B
  float* qbb = (float*)(ws + 811008);                //     1,024 B pad
  float* scg = (float*)(ws + 812032);                //     2,359,296 B
  float* scp = (float*)(ws + 3171328);               //     9,437,184 B
  float* wfp = (float*)(ws + 12608512);              //     1,769,472 B
  int* bucket = (int*)(ws + 14377984);               //     2,359,296 B
  float* Ybuf = (float*)(ws + 16737280);             //    28,311,552 B
  // end: 45,048,832 B

  q_kernel<<<dim3(T_, 12), 256, 0, stream>>>(x, Wq, bq, qbuf);
  sprj_kernel<<<NBLK_, 256, 0, stream>>>(qbuf, Wkv, bkv, sprjT, qbb);
  score_kernel<<<dim3(B_, 16, 4), 256, 0, stream>>>(x, sprjT, scp);
  score_reduce<<<dim3(NBLK_, 4), 256, 0, stream>>>(scp, qbb, scg);
  topk_kernel<<<NBLK_, 256, 0, stream>>>(scg, ibuf, wbuf);
  hipMemsetAsync(bucket, 0, (size_t)B_ * M_ * 36 * 4, stream);
  bucket_build<<<NBLK_, 256, 0, stream>>>(ibuf, bucket);
  wfeat_kernel<<<dim3(NBLK_, 4, 3), 256, 0, stream>>>(x, ibuf, wbuf, wfp);
  attn_token_kernel<<<NBLK_, 256, 0, stream>>>(wfp, Wkv, bkv, atbuf);
  token_out<<<dim3(T_, 12), 256, 0, stream>>>(atbuf, Wexp, out);
  for (int b = 0; b < B_; ++b) {
    scatter_mfma<<<dim3(36, 4, 4), 256, 0, stream>>>(x, Wexp, ibuf, wbuf, Ybuf, b);
    combine_kernel<<<M_ / 4, 256, 0, stream>>>(Ybuf, bucket, out, b);
  }
}

// Round 11
// 186.815 us; speedup vs baseline: 1.2030x; 1.0852x over previous
//
#include <hip/hip_runtime.h>
#include <hip/hip_bf16.h>

#define B_ 4
#define T_ 3
#define M_ 4096
#define C_ 768
#define H_ 12
#define K_ 256
#define HD_ 64
#define TM_ 4099      // T_ + M_
#define SCALE_ 0.125f // HD^-0.5
#define NBLK_ 144     // B*H*T, blk = b*36 + h*3 + t, th = h*3+t

typedef __attribute__((ext_vector_type(8))) short bf16x8;
typedef __attribute__((ext_vector_type(4))) float f32x4;

// order-preserving float->uint key (larger float -> larger key)
__device__ __forceinline__ unsigned keyf(float f) {
  unsigned u = __float_as_uint(f);
  return (u & 0x80000000u) ? ~u : (u | 0x80000000u);
}

__device__ __forceinline__ unsigned short f2bf(float f) { // RNE
  unsigned u = __float_as_uint(f);
  unsigned r = (u + 0x7FFFu + ((u >> 16) & 1u)) >> 16;
  return (unsigned short)r;
}
__device__ __forceinline__ unsigned pk2(float a, float b) {
  return (unsigned)f2bf(a) | ((unsigned)f2bf(b) << 16);
}

__device__ __forceinline__ int block_excl_scan256(int v, int tid, int* sbuf) {
  sbuf[tid] = v;
  __syncthreads();
  #pragma unroll
  for (int off = 1; off < 256; off <<= 1) {
    int add = (tid >= off) ? sbuf[tid - off] : 0;
    __syncthreads();
    sbuf[tid] += add;
    __syncthreads();
  }
  int inc = sbuf[tid];
  __syncthreads();
  return inc - v;
}

// ---------- kernels ----------

// q[b,t,d] = sum_c x[b,t,c] * Wq[t,d,c] + bq[t,d]
// grid = (T, 12 dchunks of 64), block = 256. Reads Wq once (4 b per block).
__global__ __launch_bounds__(256) void q_kernel(const float* __restrict__ x,
                                                const float* __restrict__ Wq,
                                                const float* __restrict__ bq,
                                                float* __restrict__ qbuf) {
  int t = blockIdx.x;
  int d0 = blockIdx.y * 64;
  int tid = threadIdx.x;
  __shared__ float ar[B_][C_];
  for (int i = tid; i < B_ * C_; i += 256) {
    int bb = i / C_, c = i % C_;
    ar[bb][c] = x[((size_t)(bb * TM_ + t)) * C_ + c];
  }
  __syncthreads();
  int grp = tid >> 4, ln = tid & 15;
  #pragma unroll
  for (int j = 0; j < 4; ++j) {
    int d = d0 + grp * 4 + j;
    const float4* wr = (const float4*)(Wq + ((size_t)t * C_ + d) * C_);
    float a0 = 0.f, a1 = 0.f, a2 = 0.f, a3 = 0.f;
    #pragma unroll
    for (int it = 0; it < 12; ++it) {
      float4 w4 = wr[ln + 16 * it];
      const float4 x0 = *(const float4*)&ar[0][(ln + 16 * it) * 4];
      const float4 x1 = *(const float4*)&ar[1][(ln + 16 * it) * 4];
      const float4 x2 = *(const float4*)&ar[2][(ln + 16 * it) * 4];
      const float4 x3 = *(const float4*)&ar[3][(ln + 16 * it) * 4];
      a0 += w4.x * x0.x + w4.y * x0.y + w4.z * x0.z + w4.w * x0.w;
      a1 += w4.x * x1.x + w4.y * x1.y + w4.z * x1.z + w4.w * x1.w;
      a2 += w4.x * x2.x + w4.y * x2.y + w4.z * x2.z + w4.w * x2.w;
      a3 += w4.x * x3.x + w4.y * x3.y + w4.z * x3.z + w4.w * x3.w;
    }
    #pragma unroll
    for (int off = 1; off < 16; off <<= 1) {
      a0 += __shfl_xor(a0, off, 16);
      a1 += __shfl_xor(a1, off, 16);
      a2 += __shfl_xor(a2, off, 16);
      a3 += __shfl_xor(a3, off, 16);
    }
    if (ln == 0) {
      float bqv = bq[t * C_ + d];
      qbuf[(size_t)(0 * T_ + t) * C_ + d] = a0 + bqv;
      qbuf[(size_t)(1 * T_ + t) * C_ + d] = a1 + bqv;
      qbuf[(size_t)(2 * T_ + t) * C_ + d] = a2 + bqv;
      qbuf[(size_t)(3 * T_ + t) * C_ + d] = a3 + bqv;
    }
  }
}

// sprjT[(b*768+c)*36 + j] = sum_{i<64} q[b,t,h*64+i] * Wkv[h*64+i, c]
// qbb[blk] = sum_{i<64} q[b,t,h*64+i] * bkv[h*64+i]
__global__ __launch_bounds__(256) void sprj_kernel(const float* __restrict__ qbuf,
                                                   const float* __restrict__ Wkv,
                                                   const float* __restrict__ bkv,
                                                   float* __restrict__ sprjT,
                                                   float* __restrict__ qbb) {
  int blk = blockIdx.x;
  int j = blk % 36;
  int b = blk / 36;
  int t = j % T_;
  int h = j / T_;
  int tid = threadIdx.x;
  __shared__ float qs[HD_];
  if (tid < HD_) qs[tid] = qbuf[((size_t)(b * T_ + t)) * C_ + h * HD_ + tid];
  __syncthreads();
  if (tid == 0) {
    float s = 0.f;
    for (int i = 0; i < HD_; ++i) s += qs[i] * bkv[h * HD_ + i];
    qbb[blk] = s;
  }
  float a0 = 0.f, a1 = 0.f, a2 = 0.f;
  for (int i = 0; i < HD_; ++i) {
    const float* wr = Wkv + ((size_t)(h * HD_ + i)) * C_;
    float qi = qs[i];
    a0 += qi * wr[tid];
    a1 += qi * wr[tid + 256];
    a2 += qi * wr[tid + 512];
  }
  sprjT[((size_t)b * C_ + tid) * 36 + j] = a0;
  sprjT[((size_t)b * C_ + tid + 256) * 36 + j] = a1;
  sprjT[((size_t)b * C_ + tid + 512) * 36 + j] = a2;
}

// score partials: scp[(cc*144 + b*36 + j)*M + m] = partial dot over 64 c's.
// grid = (B, 16 m-tiles of 256, 12 c-chunks of 64), block = 256.
// 768 blocks -> 3 blocks/CU (12 waves/CU) for latency hiding; every feat
// element still read exactly once.
__global__ __launch_bounds__(256) void score_kernel(const float* __restrict__ x,
                                                    const float* __restrict__ sprjT,
                                                    float* __restrict__ scp) {
  int b = blockIdx.x;
  int m0 = blockIdx.y * 256;
  int cc = blockIdx.z;
  int tid = threadIdx.x;

  __shared__ float fl[32][256]; // [c][m]

  float acc[36];
  #pragma unroll
  for (int j = 0; j < 36; ++j) acc[j] = 0.f;

  const float* fr0 = x + ((size_t)(b * TM_ + T_ + m0 + tid)) * C_ + cc * 64;

  for (int kc = 0; kc < 2; ++kc) {
    float4 v[8];
    const float4* fr = (const float4*)(fr0 + kc * 32);
    #pragma unroll
    for (int i = 0; i < 8; ++i) v[i] = fr[i];
    __syncthreads();
    #pragma unroll
    for (int i = 0; i < 8; ++i) {
      fl[i * 4 + 0][tid] = v[i].x;
      fl[i * 4 + 1][tid] = v[i].y;
      fl[i * 4 + 2][tid] = v[i].z;
      fl[i * 4 + 3][tid] = v[i].w;
    }
    __syncthreads();
    const float* sp = sprjT + ((size_t)b * C_ + cc * 64 + kc * 32) * 36;
    #pragma unroll 4
    for (int k = 0; k < 32; ++k) {
      float f = fl[k][tid];
      const float* sr = sp + k * 36; // uniform -> s_load
      #pragma unroll
      for (int j = 0; j < 36; ++j) acc[j] += f * sr[j];
    }
  }
  float* op = scp + ((size_t)cc * NBLK_ + (size_t)b * 36) * M_ + m0 + tid;
  #pragma unroll
  for (int j = 0; j < 36; ++j) op[(size_t)j * M_] = acc[j];
}

// scg[blk][m] = (sum_cc scp + qbb[blk]) * SCALE. grid = (144, 4), block 256.
__global__ __launch_bounds__(256) void score_reduce(const float* __restrict__ scp,
                                                    const float* __restrict__ qbb,
                                                    float* __restrict__ scg) {
  int blk = blockIdx.x;
  int m = blockIdx.y * 1024 + threadIdx.x * 4;
  float qb = qbb[blk];
  float4 s = make_float4(qb, qb, qb, qb);
  #pragma unroll
  for (int cc = 0; cc < 12; ++cc) {
    float4 a = *(const float4*)&scp[((size_t)cc * NBLK_ + blk) * M_ + m];
    s.x += a.x; s.y += a.y; s.z += a.z; s.w += a.w;
  }
  float4 o;
  o.x = s.x * SCALE_;
  o.y = s.y * SCALE_;
  o.z = s.z * SCALE_;
  o.w = s.w * SCALE_;
  *(float4*)&scg[(size_t)blk * M_ + m] = o;
}

// Per blk: exact top-K via radix select (index-ordered ties, = lax.top_k),
// softmax over selected; writes ibuf/wbuf. grid = 144, block = 256.
__global__ __launch_bounds__(256) void topk_kernel(const float* __restrict__ scg,
                                                   int* __restrict__ ibuf,
                                                   float* __restrict__ wbuf) {
  int blk = blockIdx.x;
  int tid = threadIdx.x;

  __shared__ float sc[M_];
  __shared__ unsigned hist[256];
  __shared__ int sbuf[256];
  __shared__ int selm[K_];
  __shared__ float red[256];
  __shared__ int sh_bin, sh_rem;

  const float4* srow = (const float4*)(scg + (size_t)blk * M_);
  for (int i = tid; i < M_ / 4; i += 256) ((float4*)sc)[i] = srow[i];
  __syncthreads();

  // ---- radix select: find K-th largest key ----
  unsigned prefix = 0;
  int remaining = K_;
  for (int shift = 24; shift >= 0; shift -= 8) {
    hist[tid] = 0;
    __syncthreads();
    unsigned pmask = (shift == 24) ? 0u : (0xFFFFFFFFu << (shift + 8));
    #pragma unroll 4
    for (int i = 0; i < 16; ++i) {
      unsigned k = keyf(sc[tid * 16 + i]);
      if ((k & pmask) == prefix) atomicAdd(&hist[(k >> shift) & 255u], 1u);
    }
    __syncthreads();
    int bin = 255 - tid;
    int v = (int)hist[bin];
    int cex = block_excl_scan256(v, tid, sbuf);
    if (cex < remaining && cex + v >= remaining) {
      sh_bin = bin;
      sh_rem = remaining - cex;
    }
    __syncthreads();
    prefix |= ((unsigned)sh_bin) << shift;
    remaining = sh_rem;
    __syncthreads();
  }
  const unsigned tau = prefix;
  const int r = remaining;      // # of ==tau entries to keep (lowest indices)
  const int cgt = K_ - r;       // # of >tau entries

  // ---- compact selection in ascending-index order (deterministic) ----
  int base = tid * 16;
  int myCnt = 0, myTie = 0;
  #pragma unroll
  for (int i = 0; i < 16; i++) {
    unsigned k = keyf(sc[base + i]);
    myCnt += (k > tau);
    myTie += (k == tau);
  }
  int offs = block_excl_scan256(myCnt, tid, sbuf);
  int toffs = block_excl_scan256(myTie, tid, sbuf);
  for (int i = 0; i < 16; i++) {
    int m = base + i;
    unsigned k = keyf(sc[m]);
    if (k > tau) {
      selm[offs++] = m;
    } else if (k == tau) {
      if (toffs < r) selm[cgt + toffs] = m;
      toffs++;
    }
  }
  __syncthreads();

  // ---- softmax over the K selected ----
  int m = selm[tid];
  float val = sc[m];
  red[tid] = val;
  __syncthreads();
  for (int off = 128; off > 0; off >>= 1) {
    if (tid < off) red[tid] = fmaxf(red[tid], red[tid + off]);
    __syncthreads();
  }
  float mx = red[0];
  __syncthreads();
  float e = expf(val - mx);
  red[tid] = e;
  __syncthreads();
  for (int off = 128; off > 0; off >>= 1) {
    if (tid < off) red[tid] += red[tid + off];
    __syncthreads();
  }
  ibuf[(size_t)blk * K_ + tid] = m;
  wbuf[(size_t)blk * K_ + tid] = e / red[0];
}

// wfp[blk*4+kc][c] = sum_{k in chunk} w_k * feat[m_k, c]
// grid = (144, 4, 3 c-segments), block = 256
__global__ __launch_bounds__(256) void wfeat_kernel(const float* __restrict__ x,
                                                    const int* __restrict__ ibuf,
                                                    const float* __restrict__ wbuf,
                                                    float* __restrict__ wfp) {
  int blk = blockIdx.x, kc = blockIdx.y, cseg = blockIdx.z;
  int b = blk / 36;
  int tid = threadIdx.x;
  __shared__ int ml[64];
  __shared__ float wl[64];
  if (tid < 64) {
    ml[tid] = ibuf[(size_t)blk * K_ + kc * 64 + tid];
    wl[tid] = wbuf[(size_t)blk * K_ + kc * 64 + tid];
  }
  __syncthreads();
  int c = cseg * 256 + tid;
  const float* fbase = x + ((size_t)b * TM_ + T_) * C_ + c;
  float a = 0.f;
  #pragma unroll 4
  for (int kk = 0; kk < 64; ++kk) {
    a += wl[kk] * fbase[(size_t)ml[kk] * C_];
  }
  wfp[((size_t)blk * 4 + kc) * C_ + c] = a;
}

// attn_token[b,t,h*64+rr] = (sum_kc wfp) . Wv[row] + bv[row]; grid = 144
__global__ __launch_bounds__(256) void attn_token_kernel(
    const float* __restrict__ wfp, const float* __restrict__ Wkv,
    const float* __restrict__ bkv, float* __restrict__ atbuf) {
  int blk = blockIdx.x;
  int t = blk % T_;
  int h = (blk / T_) % H_;
  int b = blk / (T_ * H_);
  int tid = threadIdx.x;
  __shared__ float wfeat[C_];
  const float* p0 = wfp + ((size_t)blk * 4) * C_;
  #pragma unroll
  for (int j = 0; j < 3; ++j) {
    int c = tid + j * 256;
    wfeat[c] = p0[c] + p0[C_ + c] + p0[2 * C_ + c] + p0[3 * C_ + c];
  }
  __syncthreads();
  int grp = tid >> 4, ln = tid & 15;
  for (int rr = grp; rr < HD_; rr += 16) {
    const float4* wr = (const float4*)(Wkv + ((size_t)(C_ + h * HD_ + rr)) * C_);
    float acc = 0.f;
    #pragma unroll
    for (int it = 0; it < 12; ++it) {
      float4 wv = wr[ln + it * 16];
      const float4 fv = *(const float4*)&wfeat[(ln + it * 16) * 4];
      acc += wv.x * fv.x + wv.y * fv.y + wv.z * fv.z + wv.w * fv.w;
    }
    acc += __shfl_xor(acc, 1, 16);
    acc += __shfl_xor(acc, 2, 16);
    acc += __shfl_xor(acc, 4, 16);
    acc += __shfl_xor(acc, 8, 16);
    if (ln == 0)
      atbuf[((size_t)(b * T_ + t)) * C_ + h * HD_ + rr] =
          acc + bkv[C_ + h * HD_ + rr];
  }
}

// token_output[b,t,d] = sum_c attn_token[b,t,c] * Wexp[t,d,c]
// grid = (T, 12 dchunks of 64), block 256. Fully writes task rows of out.
__global__ __launch_bounds__(256) void token_out(const float* __restrict__ atbuf,
                                                 const float* __restrict__ Wexp,
                                                 float* __restrict__ out) {
  int t = blockIdx.x;
  int d0 = blockIdx.y * 64;
  int tid = threadIdx.x;
  __shared__ float ar[B_][C_];
  for (int i = tid; i < B_ * C_; i += 256) {
    int bb = i / C_, c = i % C_;
    ar[bb][c] = atbuf[((size_t)(bb * T_ + t)) * C_ + c];
  }
  __syncthreads();
  int grp = tid >> 4, ln = tid & 15;
  #pragma unroll
  for (int j = 0; j < 4; ++j) {
    int d = d0 + grp * 4 + j;
    const float4* wr = (const float4*)(Wexp + ((size_t)t * C_ + d) * C_);
    float a0 = 0.f, a1 = 0.f, a2 = 0.f, a3 = 0.f;
    #pragma unroll
    for (int it = 0; it < 12; ++it) {
      float4 w4 = wr[ln + 16 * it];
      const float4 x0 = *(const float4*)&ar[0][(ln + 16 * it) * 4];
      const float4 x1 = *(const float4*)&ar[1][(ln + 16 * it) * 4];
      const float4 x2 = *(const float4*)&ar[2][(ln + 16 * it) * 4];
      const float4 x3 = *(const float4*)&ar[3][(ln + 16 * it) * 4];
      a0 += w4.x * x0.x + w4.y * x0.y + w4.z * x0.z + w4.w * x0.w;
      a1 += w4.x * x1.x + w4.y * x1.y + w4.z * x1.z + w4.w * x1.w;
      a2 += w4.x * x2.x + w4.y * x2.y + w4.z * x2.z + w4.w * x2.w;
      a3 += w4.x * x3.x + w4.y * x3.y + w4.z * x3.z + w4.w * x3.w;
    }
    #pragma unroll
    for (int off = 1; off < 16; off <<= 1) {
      a0 += __shfl_xor(a0, off, 16);
      a1 += __shfl_xor(a1, off, 16);
      a2 += __shfl_xor(a2, off, 16);
      a3 += __shfl_xor(a3, off, 16);
    }
    if (ln == 0) {
      out[((size_t)0 * TM_ + t) * C_ + d] = a0;
      out[((size_t)1 * TM_ + t) * C_ + d] = a1;
      out[((size_t)2 * TM_ + t) * C_ + d] = a2;
      out[((size_t)3 * TM_ + t) * C_ + d] = a3;
    }
  }
}

// Inverted index: bucket[(b*M+m)*36 + th] = sel+1 (0 = none).
// Per (b,m) each th contributes at most one sel (top-k indices distinct) ->
// no atomics, fully deterministic. grid = 144, block = 256.
__global__ void bucket_build(const int* __restrict__ ibuf,
                             int* __restrict__ bucket) {
  int bht = blockIdx.x;
  int b = bht / 36, th = bht % 36;
  int sel = threadIdx.x;
  int m = ibuf[(size_t)bht * K_ + sel];
  bucket[((size_t)b * M_ + m) * 36 + th] = sel + 1;
}

// Per-b MFMA GEMM into dense Y (no atomics):
//   Y[th][sel][d] = w_sel * feat[b, m_sel, h64 block] @ Wexp[t,:,h64 block]^T
// grid = (36 th, 4 ks, 4 dc), block = 256 (4 waves).
__global__ __launch_bounds__(256) void scatter_mfma(
    const float* __restrict__ x, const float* __restrict__ Wexp,
    const int* __restrict__ ibuf, const float* __restrict__ wbuf,
    float* __restrict__ Y, int b) {
  int th = blockIdx.x;
  int h = th / T_, t = th % T_;
  int ks = blockIdx.y;
  int dc = blockIdx.z;
  int bht = b * 36 + th;
  int tid = threadIdx.x;

  __shared__ unsigned short fw[64][72];
  __shared__ unsigned short wt[192][72];

  // stage fw (bf16 of w * feat slice): thread = (kk, 16-c chunk)
  {
    int kk = tid >> 2, cp = (tid & 3) * 16;
    int sel = ks * 64 + kk;
    int m = ibuf[(size_t)bht * K_ + sel];
    float w = wbuf[(size_t)bht * K_ + sel];
    const float* fr = x + ((size_t)(b * TM_) + T_ + m) * C_ + h * HD_ + cp;
    float4 f0 = *(const float4*)(fr + 0);
    float4 f1 = *(const float4*)(fr + 4);
    float4 f2 = *(const float4*)(fr + 8);
    float4 f3 = *(const float4*)(fr + 12);
    uint4 u0 = make_uint4(pk2(f0.x * w, f0.y * w), pk2(f0.z * w, f0.w * w),
                          pk2(f1.x * w, f1.y * w), pk2(f1.z * w, f1.w * w));
    uint4 u1 = make_uint4(pk2(f2.x * w, f2.y * w), pk2(f2.z * w, f2.w * w),
                          pk2(f3.x * w, f3.y * w), pk2(f3.z * w, f3.w * w));
    *(uint4*)&fw[kk][cp] = u0;
    *(uint4*)&fw[kk][cp + 8] = u1;
  }
  // stage wt[dd][c] = bf16(Wexp[t, dc*192+dd, h*64+c]) — coalesced rows
  {
    #pragma unroll
    for (int r2 = 0; r2 < 3; ++r2) {
      int idx = r2 * 256 + tid;
      int dd = idx >> 2, cq = (idx & 3) * 16;
      const float* wr =
          Wexp + ((size_t)t * C_ + dc * 192 + dd) * C_ + h * HD_ + cq;
      float4 f0 = *(const float4*)(wr + 0);
      float4 f1 = *(const float4*)(wr + 4);
      float4 f2 = *(const float4*)(wr + 8);
      float4 f3 = *(const float4*)(wr + 12);
      uint4 u0 = make_uint4(pk2(f0.x, f0.y), pk2(f0.z, f0.w),
                            pk2(f1.x, f1.y), pk2(f1.z, f1.w));
      uint4 u1 = make_uint4(pk2(f2.x, f2.y), pk2(f2.z, f2.w),
                            pk2(f3.x, f3.y), pk2(f3.z, f3.w));
      *(uint4*)&wt[dd][cq] = u0;
      *(uint4*)&wt[dd][cq + 8] = u1;
    }
  }
  __syncthreads();

  int lane = tid & 63, wave = tid >> 6;
  int lrow = lane & 15, lk8 = (lane >> 4) * 8, g4 = (lane >> 4) * 4;

  f32x4 acc[12];
  #pragma unroll
  for (int n = 0; n < 12; ++n) acc[n] = (f32x4){0.f, 0.f, 0.f, 0.f};

  #pragma unroll
  for (int ks2 = 0; ks2 < 2; ++ks2) {
    bf16x8 a = *(const bf16x8*)&fw[wave * 16 + lrow][ks2 * 32 + lk8];
    #pragma unroll
    for (int n = 0; n < 12; ++n) {
      bf16x8 bfr = *(const bf16x8*)&wt[n * 16 + lrow][ks2 * 32 + lk8];
      acc[n] = __builtin_amdgcn_mfma_f32_16x16x32_bf16(a, bfr, acc[n], 0, 0, 0);
    }
  }

  // epilogue: D col = lane&15 (d), row = (lane>>4)*4 + q (local row).
  // Plain coalesced stores to Y — no atomics.
  #pragma unroll
  for (int n = 0; n < 12; ++n) {
    int d = dc * 192 + n * 16 + lrow;
    #pragma unroll
    for (int q = 0; q < 4; ++q) {
      int row = ks * 64 + wave * 16 + g4 + q;
      Y[((size_t)th * K_ + row) * C_ + d] = acc[n][q];
    }
  }
}

// Combine: out[b, T+m, :] = sum over active th (ascending, deterministic) of
// Y[th][sel][:]. Rows with no contributions get zeros (replaces zero_out).
// grid = M/4 blocks, block = 256 (wave per m row).
__global__ __launch_bounds__(256) void combine_kernel(
    const float* __restrict__ Y, const int* __restrict__ bucket,
    float* __restrict__ out, int b) {
  int wave = threadIdx.x >> 6, lane = threadIdx.x & 63;
  int m = blockIdx.x * 4 + wave;
  const int* bk = bucket + ((size_t)b * M_ + m) * 36;
  int v = (lane < 36) ? bk[lane] : 0;
  unsigned long long mask = __ballot(v > 0);
  float4 a0 = make_float4(0.f, 0.f, 0.f, 0.f);
  float4 a1 = make_float4(0.f, 0.f, 0.f, 0.f);
  float4 a2 = make_float4(0.f, 0.f, 0.f, 0.f);
  while (mask) {
    int th = __ffsll((unsigned long long)mask) - 1;
    mask &= mask - 1;
    int sel = __shfl(v, th) - 1;
    const float* yr = Y + ((size_t)th * K_ + sel) * C_;
    float4 r0 = *(const float4*)(yr + lane * 4);
    float4 r1 = *(const float4*)(yr + 256 + lane * 4);
    float4 r2 = *(const float4*)(yr + 512 + lane * 4);
    a0.x += r0.x; a0.y += r0.y; a0.z += r0.z; a0.w += r0.w;
    a1.x += r1.x; a1.y += r1.y; a1.z += r1.z; a1.w += r1.w;
    a2.x += r2.x; a2.y += r2.y; a2.z += r2.z; a2.w += r2.w;
  }
  float* orow = out + ((size_t)b * TM_ + T_ + m) * C_;
  *(float4*)(orow + lane * 4) = a0;
  *(float4*)(orow + 256 + lane * 4) = a1;
  *(float4*)(orow + 512 + lane * 4) = a2;
}

// ---------- launch ----------
extern "C" void kernel_launch(void* const* d_in, const int* in_sizes, int n_in,
                              void* d_out, int out_size, void* d_ws, size_t ws_size,
                              hipStream_t stream) {
  (void)in_sizes; (void)n_in; (void)ws_size; (void)out_size;
  const float* x = (const float*)d_in[0];
  const float* Wq = (const float*)d_in[1];
  const float* bq = (const float*)d_in[2];
  const float* Wkv = (const float*)d_in[3];
  const float* bkv = (const float*)d_in[4];
  const float* Wexp = (const float*)d_in[5];
  float* out = (float*)d_out;

  // workspace layout (~35.6 MiB total; scp and Ybuf alias — disjoint lifetimes)
  char* ws = (char*)d_ws;
  float* qbuf = (float*)ws;                          //        36,864 B
  float* atbuf = (float*)(ws + 36864);               //        36,864 B
  int* ibuf = (int*)(ws + 73728);                    //       147,456 B
  float* wbuf = (float*)(ws + 221184);               //       147,456 B
  float* sprjT = (float*)(ws + 368640);              //       442,368 B
  float* qbb = (float*)(ws + 811008);                //     1,024 B pad
  float* scg = (float*)(ws + 812032);                //     2,359,296 B
  float* scp = (float*)(ws + 3171328);               //    28,311,552 B (12 partials)
  float* Ybuf = (float*)(ws + 3171328);              //    28,311,552 B (aliases scp)
  float* wfp = (float*)(ws + 31482880);              //     1,769,472 B
  int* bucket = (int*)(ws + 33252352);               //     2,359,296 B
  // end: 35,611,648 B

  q_kernel<<<dim3(T_, 12), 256, 0, stream>>>(x, Wq, bq, qbuf);
  sprj_kernel<<<NBLK_, 256, 0, stream>>>(qbuf, Wkv, bkv, sprjT, qbb);
  score_kernel<<<dim3(B_, 16, 12), 256, 0, stream>>>(x, sprjT, scp);
  score_reduce<<<dim3(NBLK_, 4), 256, 0, stream>>>(scp, qbb, scg);
  topk_kernel<<<NBLK_, 256, 0, stream>>>(scg, ibuf, wbuf);
  hipMemsetAsync(bucket, 0, (size_t)B_ * M_ * 36 * 4, stream);
  bucket_build<<<NBLK_, 256, 0, stream>>>(ibuf, bucket);
  wfeat_kernel<<<dim3(NBLK_, 4, 3), 256, 0, stream>>>(x, ibuf, wbuf, wfp);
  attn_token_kernel<<<NBLK_, 256, 0, stream>>>(wfp, Wkv, bkv, atbuf);
  token_out<<<dim3(T_, 12), 256, 0, stream>>>(atbuf, Wexp, out);
  for (int b = 0; b < B_; ++b) {
    scatter_mfma<<<dim3(36, 4, 4), 256, 0, stream>>>(x, Wexp, ibuf, wbuf, Ybuf, b);
    combine_kernel<<<M_ / 4, 256, 0, stream>>>(Ybuf, bucket, out, b);
  }
}

// Round 12
// 143.571 us; speedup vs baseline: 1.5653x; 1.3012x over previous
//
#include <hip/hip_runtime.h>
#include <hip/hip_bf16.h>

#define B_ 4
#define T_ 3
#define M_ 4096
#define C_ 768
#define H_ 12
#define K_ 256
#define HD_ 64
#define TM_ 4099      // T_ + M_
#define SCALE_ 0.125f // HD^-0.5
#define NBLK_ 144     // B*H*T, blk = b*36 + h*3 + t, th = h*3+t

typedef __attribute__((ext_vector_type(8))) short bf16x8;
typedef __attribute__((ext_vector_type(4))) float f32x4;

// order-preserving float->uint key (larger float -> larger key)
__device__ __forceinline__ unsigned keyf(float f) {
  unsigned u = __float_as_uint(f);
  return (u & 0x80000000u) ? ~u : (u | 0x80000000u);
}

__device__ __forceinline__ unsigned short f2bf(float f) { // RNE
  unsigned u = __float_as_uint(f);
  unsigned r = (u + 0x7FFFu + ((u >> 16) & 1u)) >> 16;
  return (unsigned short)r;
}
__device__ __forceinline__ float bf2f(unsigned short u) {
  return __uint_as_float(((unsigned)u) << 16);
}
__device__ __forceinline__ unsigned pk2(float a, float b) {
  return (unsigned)f2bf(a) | ((unsigned)f2bf(b) << 16);
}

// block exclusive scan over 256 threads: wave shfl scan + 4-word combine.
__device__ __forceinline__ int block_excl_scan256(int v, int tid, int* sbuf) {
  int lane = tid & 63, wid = tid >> 6;
  int x = v;
  #pragma unroll
  for (int off = 1; off < 64; off <<= 1) {
    int y = __shfl_up(x, off, 64);
    if (lane >= off) x += y;
  }
  if (lane == 63) sbuf[wid] = x;
  __syncthreads();
  int base = 0;
  #pragma unroll
  for (int w = 0; w < 3; ++w) base += (w < wid) ? sbuf[w] : 0;
  __syncthreads(); // safe reuse of sbuf by next call
  return base + x - v;
}

// ---------- kernels ----------

// q[b,t,d] = sum_c x[b,t,c] * Wq[t,d,c] + bq[t,d]
// grid = (T, 12 dchunks of 64), block = 256. Reads Wq once (4 b per block).
__global__ __launch_bounds__(256) void q_kernel(const float* __restrict__ x,
                                                const float* __restrict__ Wq,
                                                const float* __restrict__ bq,
                                                float* __restrict__ qbuf) {
  int t = blockIdx.x;
  int d0 = blockIdx.y * 64;
  int tid = threadIdx.x;
  __shared__ float ar[B_][C_];
  for (int i = tid; i < B_ * C_; i += 256) {
    int bb = i / C_, c = i % C_;
    ar[bb][c] = x[((size_t)(bb * TM_ + t)) * C_ + c];
  }
  __syncthreads();
  int grp = tid >> 4, ln = tid & 15;
  #pragma unroll
  for (int j = 0; j < 4; ++j) {
    int d = d0 + grp * 4 + j;
    const float4* wr = (const float4*)(Wq + ((size_t)t * C_ + d) * C_);
    float a0 = 0.f, a1 = 0.f, a2 = 0.f, a3 = 0.f;
    #pragma unroll
    for (int it = 0; it < 12; ++it) {
      float4 w4 = wr[ln + 16 * it];
      const float4 x0 = *(const float4*)&ar[0][(ln + 16 * it) * 4];
      const float4 x1 = *(const float4*)&ar[1][(ln + 16 * it) * 4];
      const float4 x2 = *(const float4*)&ar[2][(ln + 16 * it) * 4];
      const float4 x3 = *(const float4*)&ar[3][(ln + 16 * it) * 4];
      a0 += w4.x * x0.x + w4.y * x0.y + w4.z * x0.z + w4.w * x0.w;
      a1 += w4.x * x1.x + w4.y * x1.y + w4.z * x1.z + w4.w * x1.w;
      a2 += w4.x * x2.x + w4.y * x2.y + w4.z * x2.z + w4.w * x2.w;
      a3 += w4.x * x3.x + w4.y * x3.y + w4.z * x3.z + w4.w * x3.w;
    }
    #pragma unroll
    for (int off = 1; off < 16; off <<= 1) {
      a0 += __shfl_xor(a0, off, 16);
      a1 += __shfl_xor(a1, off, 16);
      a2 += __shfl_xor(a2, off, 16);
      a3 += __shfl_xor(a3, off, 16);
    }
    if (ln == 0) {
      float bqv = bq[t * C_ + d];
      qbuf[(size_t)(0 * T_ + t) * C_ + d] = a0 + bqv;
      qbuf[(size_t)(1 * T_ + t) * C_ + d] = a1 + bqv;
      qbuf[(size_t)(2 * T_ + t) * C_ + d] = a2 + bqv;
      qbuf[(size_t)(3 * T_ + t) * C_ + d] = a3 + bqv;
    }
  }
}

// sprjT[(b*768+c)*36 + j] = sum_{i<64} q[b,t,h*64+i] * Wkv[h*64+i, c]
// qbb[blk] = sum_{i<64} q[b,t,h*64+i] * bkv[h*64+i]
__global__ __launch_bounds__(256) void sprj_kernel(const float* __restrict__ qbuf,
                                                   const float* __restrict__ Wkv,
                                                   const float* __restrict__ bkv,
                                                   float* __restrict__ sprjT,
                                                   float* __restrict__ qbb) {
  int blk = blockIdx.x;
  int j = blk % 36;
  int b = blk / 36;
  int t = j % T_;
  int h = j / T_;
  int tid = threadIdx.x;
  __shared__ float qs[HD_];
  if (tid < HD_) qs[tid] = qbuf[((size_t)(b * T_ + t)) * C_ + h * HD_ + tid];
  __syncthreads();
  if (tid == 0) {
    float s = 0.f;
    for (int i = 0; i < HD_; ++i) s += qs[i] * bkv[h * HD_ + i];
    qbb[blk] = s;
  }
  float a0 = 0.f, a1 = 0.f, a2 = 0.f;
  for (int i = 0; i < HD_; ++i) {
    const float* wr = Wkv + ((size_t)(h * HD_ + i)) * C_;
    float qi = qs[i];
    a0 += qi * wr[tid];
    a1 += qi * wr[tid + 256];
    a2 += qi * wr[tid + 512];
  }
  sprjT[((size_t)b * C_ + tid) * 36 + j] = a0;
  sprjT[((size_t)b * C_ + tid + 256) * 36 + j] = a1;
  sprjT[((size_t)b * C_ + tid + 512) * 36 + j] = a2;
}

// score partials: scp[(cc*144 + b*36 + j)*M + m] = partial dot over 64 c's.
// grid = (B, 16 m-tiles of 256, 12 c-chunks of 64), block = 256.
__global__ __launch_bounds__(256) void score_kernel(const float* __restrict__ x,
                                                    const float* __restrict__ sprjT,
                                                    float* __restrict__ scp) {
  int b = blockIdx.x;
  int m0 = blockIdx.y * 256;
  int cc = blockIdx.z;
  int tid = threadIdx.x;

  __shared__ float fl[32][256]; // [c][m]

  float acc[36];
  #pragma unroll
  for (int j = 0; j < 36; ++j) acc[j] = 0.f;

  const float* fr0 = x + ((size_t)(b * TM_ + T_ + m0 + tid)) * C_ + cc * 64;

  for (int kc = 0; kc < 2; ++kc) {
    float4 v[8];
    const float4* fr = (const float4*)(fr0 + kc * 32);
    #pragma unroll
    for (int i = 0; i < 8; ++i) v[i] = fr[i];
    __syncthreads();
    #pragma unroll
    for (int i = 0; i < 8; ++i) {
      fl[i * 4 + 0][tid] = v[i].x;
      fl[i * 4 + 1][tid] = v[i].y;
      fl[i * 4 + 2][tid] = v[i].z;
      fl[i * 4 + 3][tid] = v[i].w;
    }
    __syncthreads();
    const float* sp = sprjT + ((size_t)b * C_ + cc * 64 + kc * 32) * 36;
    #pragma unroll 4
    for (int k = 0; k < 32; ++k) {
      float f = fl[k][tid];
      const float* sr = sp + k * 36; // uniform -> s_load
      #pragma unroll
      for (int j = 0; j < 36; ++j) acc[j] += f * sr[j];
    }
  }
  float* op = scp + ((size_t)cc * NBLK_ + (size_t)b * 36) * M_ + m0 + tid;
  #pragma unroll
  for (int j = 0; j < 36; ++j) op[(size_t)j * M_] = acc[j];
}

// Fused score-reduce + exact top-K (radix select, index-ordered ties =
// lax.top_k) + softmax. grid = 144, block = 256.
__global__ __launch_bounds__(256) void topk_kernel(const float* __restrict__ scp,
                                                   const float* __restrict__ qbb,
                                                   int* __restrict__ ibuf,
                                                   float* __restrict__ wbuf) {
  int blk = blockIdx.x;
  int tid = threadIdx.x;

  __shared__ float sc[M_];
  __shared__ unsigned hist[256];
  __shared__ int sbuf[4];
  __shared__ int selm[K_];
  __shared__ float redf[4];
  __shared__ int sh_bin, sh_rem;

  // reduce 12 c-chunk partials (ascending cc, deterministic) + scale
  float qb = qbb[blk];
  for (int i = tid; i < M_ / 4; i += 256) {
    float4 s = make_float4(qb, qb, qb, qb);
    #pragma unroll
    for (int cc = 0; cc < 12; ++cc) {
      float4 a = *(const float4*)&scp[((size_t)cc * NBLK_ + blk) * M_ + i * 4];
      s.x += a.x; s.y += a.y; s.z += a.z; s.w += a.w;
    }
    *(float4*)&sc[i * 4] =
        make_float4(s.x * SCALE_, s.y * SCALE_, s.z * SCALE_, s.w * SCALE_);
  }
  __syncthreads();

  // ---- radix select: find K-th largest key ----
  unsigned prefix = 0;
  int remaining = K_;
  for (int shift = 24; shift >= 0; shift -= 8) {
    hist[tid] = 0;
    __syncthreads();
    unsigned pmask = (shift == 24) ? 0u : (0xFFFFFFFFu << (shift + 8));
    #pragma unroll 4
    for (int i = 0; i < 16; ++i) {
      unsigned k = keyf(sc[tid * 16 + i]);
      if ((k & pmask) == prefix) atomicAdd(&hist[(k >> shift) & 255u], 1u);
    }
    __syncthreads();
    int bin = 255 - tid;
    int v = (int)hist[bin];
    int cex = block_excl_scan256(v, tid, sbuf);
    if (cex < remaining && cex + v >= remaining) {
      sh_bin = bin;
      sh_rem = remaining - cex;
    }
    __syncthreads();
    prefix |= ((unsigned)sh_bin) << shift;
    remaining = sh_rem;
    __syncthreads();
  }
  const unsigned tau = prefix;
  const int r = remaining;      // # of ==tau entries to keep (lowest indices)
  const int cgt = K_ - r;       // # of >tau entries

  // ---- compact selection in ascending-index order (deterministic) ----
  int base = tid * 16;
  int myCnt = 0, myTie = 0;
  #pragma unroll
  for (int i = 0; i < 16; i++) {
    unsigned k = keyf(sc[base + i]);
    myCnt += (k > tau);
    myTie += (k == tau);
  }
  int offs = block_excl_scan256(myCnt, tid, sbuf);
  int toffs = block_excl_scan256(myTie, tid, sbuf);
  for (int i = 0; i < 16; i++) {
    int m = base + i;
    unsigned k = keyf(sc[m]);
    if (k > tau) {
      selm[offs++] = m;
    } else if (k == tau) {
      if (toffs < r) selm[cgt + toffs] = m;
      toffs++;
    }
  }
  __syncthreads();

  // ---- softmax over the K selected (wave reduce + 4-word combine) ----
  int m = selm[tid];
  float val = sc[m];
  float mx = val;
  #pragma unroll
  for (int off = 32; off > 0; off >>= 1) mx = fmaxf(mx, __shfl_xor(mx, off, 64));
  if ((tid & 63) == 0) redf[tid >> 6] = mx;
  __syncthreads();
  mx = fmaxf(fmaxf(redf[0], redf[1]), fmaxf(redf[2], redf[3]));
  float e = expf(val - mx);
  float sm = e;
  #pragma unroll
  for (int off = 32; off > 0; off >>= 1) sm += __shfl_xor(sm, off, 64);
  __syncthreads();
  if ((tid & 63) == 0) redf[tid >> 6] = sm;
  __syncthreads();
  sm = redf[0] + redf[1] + redf[2] + redf[3];
  ibuf[(size_t)blk * K_ + tid] = m;
  wbuf[(size_t)blk * K_ + tid] = e / sm;
}

// wfp[blk*4+kc][c] = sum_{k in chunk} w_k * feat[m_k, c]
// grid = (144, 4, 3 c-segments), block = 256
__global__ __launch_bounds__(256) void wfeat_kernel(const float* __restrict__ x,
                                                    const int* __restrict__ ibuf,
                                                    const float* __restrict__ wbuf,
                                                    float* __restrict__ wfp) {
  int blk = blockIdx.x, kc = blockIdx.y, cseg = blockIdx.z;
  int b = blk / 36;
  int tid = threadIdx.x;
  __shared__ int ml[64];
  __shared__ float wl[64];
  if (tid < 64) {
    ml[tid] = ibuf[(size_t)blk * K_ + kc * 64 + tid];
    wl[tid] = wbuf[(size_t)blk * K_ + kc * 64 + tid];
  }
  __syncthreads();
  int c = cseg * 256 + tid;
  const float* fbase = x + ((size_t)b * TM_ + T_) * C_ + c;
  float a = 0.f;
  #pragma unroll 4
  for (int kk = 0; kk < 64; ++kk) {
    a += wl[kk] * fbase[(size_t)ml[kk] * C_];
  }
  wfp[((size_t)blk * 4 + kc) * C_ + c] = a;
}

// attn_token[b,t,h*64+rr] = (sum_kc wfp) . Wv[row] + bv[row]; grid = 144
__global__ __launch_bounds__(256) void attn_token_kernel(
    const float* __restrict__ wfp, const float* __restrict__ Wkv,
    const float* __restrict__ bkv, float* __restrict__ atbuf) {
  int blk = blockIdx.x;
  int t = blk % T_;
  int h = (blk / T_) % H_;
  int b = blk / (T_ * H_);
  int tid = threadIdx.x;
  __shared__ float wfeat[C_];
  const float* p0 = wfp + ((size_t)blk * 4) * C_;
  #pragma unroll
  for (int j = 0; j < 3; ++j) {
    int c = tid + j * 256;
    wfeat[c] = p0[c] + p0[C_ + c] + p0[2 * C_ + c] + p0[3 * C_ + c];
  }
  __syncthreads();
  int grp = tid >> 4, ln = tid & 15;
  for (int rr = grp; rr < HD_; rr += 16) {
    const float4* wr = (const float4*)(Wkv + ((size_t)(C_ + h * HD_ + rr)) * C_);
    float acc = 0.f;
    #pragma unroll
    for (int it = 0; it < 12; ++it) {
      float4 wv = wr[ln + it * 16];
      const float4 fv = *(const float4*)&wfeat[(ln + it * 16) * 4];
      acc += wv.x * fv.x + wv.y * fv.y + wv.z * fv.z + wv.w * fv.w;
    }
    acc += __shfl_xor(acc, 1, 16);
    acc += __shfl_xor(acc, 2, 16);
    acc += __shfl_xor(acc, 4, 16);
    acc += __shfl_xor(acc, 8, 16);
    if (ln == 0)
      atbuf[((size_t)(b * T_ + t)) * C_ + h * HD_ + rr] =
          acc + bkv[C_ + h * HD_ + rr];
  }
}

// token_output[b,t,d] = sum_c attn_token[b,t,c] * Wexp[t,d,c]
// grid = (T, 12 dchunks of 64), block 256. Fully writes task rows of out.
__global__ __launch_bounds__(256) void token_out(const float* __restrict__ atbuf,
                                                 const float* __restrict__ Wexp,
                                                 float* __restrict__ out) {
  int t = blockIdx.x;
  int d0 = blockIdx.y * 64;
  int tid = threadIdx.x;
  __shared__ float ar[B_][C_];
  for (int i = tid; i < B_ * C_; i += 256) {
    int bb = i / C_, c = i % C_;
    ar[bb][c] = atbuf[((size_t)(bb * T_ + t)) * C_ + c];
  }
  __syncthreads();
  int grp = tid >> 4, ln = tid & 15;
  #pragma unroll
  for (int j = 0; j < 4; ++j) {
    int d = d0 + grp * 4 + j;
    const float4* wr = (const float4*)(Wexp + ((size_t)t * C_ + d) * C_);
    float a0 = 0.f, a1 = 0.f, a2 = 0.f, a3 = 0.f;
    #pragma unroll
    for (int it = 0; it < 12; ++it) {
      float4 w4 = wr[ln + 16 * it];
      const float4 x0 = *(const float4*)&ar[0][(ln + 16 * it) * 4];
      const float4 x1 = *(const float4*)&ar[1][(ln + 16 * it) * 4];
      const float4 x2 = *(const float4*)&ar[2][(ln + 16 * it) * 4];
      const float4 x3 = *(const float4*)&ar[3][(ln + 16 * it) * 4];
      a0 += w4.x * x0.x + w4.y * x0.y + w4.z * x0.z + w4.w * x0.w;
      a1 += w4.x * x1.x + w4.y * x1.y + w4.z * x1.z + w4.w * x1.w;
      a2 += w4.x * x2.x + w4.y * x2.y + w4.z * x2.z + w4.w * x2.w;
      a3 += w4.x * x3.x + w4.y * x3.y + w4.z * x3.z + w4.w * x3.w;
    }
    #pragma unroll
    for (int off = 1; off < 16; off <<= 1) {
      a0 += __shfl_xor(a0, off, 16);
      a1 += __shfl_xor(a1, off, 16);
      a2 += __shfl_xor(a2, off, 16);
      a3 += __shfl_xor(a3, off, 16);
    }
    if (ln == 0) {
      out[((size_t)0 * TM_ + t) * C_ + d] = a0;
      out[((size_t)1 * TM_ + t) * C_ + d] = a1;
      out[((size_t)2 * TM_ + t) * C_ + d] = a2;
      out[((size_t)3 * TM_ + t) * C_ + d] = a3;
    }
  }
}

// Inverted index: bucket[(b*M+m)*36 + th] = sel+1 (0 = none). No atomics.
__global__ void bucket_build(const int* __restrict__ ibuf,
                             int* __restrict__ bucket) {
  int bht = blockIdx.x;
  int b = bht / 36, th = bht % 36;
  int sel = threadIdx.x;
  int m = ibuf[(size_t)bht * K_ + sel];
  bucket[((size_t)b * M_ + m) * 36 + th] = sel + 1;
}

// All-b MFMA GEMM into dense bf16 Y (no atomics):
//   Y[bht][sel][d] = bf16( w_sel * feat[b,m_sel,h64] @ Wexp[t,:,h64]^T )
// grid = (36 th, 16 = b*4+ks, 4 dc), block = 256 (4 waves).
__global__ __launch_bounds__(256) void scatter_mfma(
    const float* __restrict__ x, const float* __restrict__ Wexp,
    const int* __restrict__ ibuf, const float* __restrict__ wbuf,
    unsigned short* __restrict__ Y) {
  int th = blockIdx.x;
  int h = th / T_, t = th % T_;
  int b = blockIdx.y >> 2, ks = blockIdx.y & 3;
  int dc = blockIdx.z;
  int bht = b * 36 + th;
  int tid = threadIdx.x;

  __shared__ unsigned short fw[64][72];
  __shared__ unsigned short wt[192][72];

  // stage fw (bf16 of w * feat slice): thread = (kk, 16-c chunk)
  {
    int kk = tid >> 2, cp = (tid & 3) * 16;
    int sel = ks * 64 + kk;
    int m = ibuf[(size_t)bht * K_ + sel];
    float w = wbuf[(size_t)bht * K_ + sel];
    const float* fr = x + ((size_t)(b * TM_) + T_ + m) * C_ + h * HD_ + cp;
    float4 f0 = *(const float4*)(fr + 0);
    float4 f1 = *(const float4*)(fr + 4);
    float4 f2 = *(const float4*)(fr + 8);
    float4 f3 = *(const float4*)(fr + 12);
    uint4 u0 = make_uint4(pk2(f0.x * w, f0.y * w), pk2(f0.z * w, f0.w * w),
                          pk2(f1.x * w, f1.y * w), pk2(f1.z * w, f1.w * w));
    uint4 u1 = make_uint4(pk2(f2.x * w, f2.y * w), pk2(f2.z * w, f2.w * w),
                          pk2(f3.x * w, f3.y * w), pk2(f3.z * w, f3.w * w));
    *(uint4*)&fw[kk][cp] = u0;
    *(uint4*)&fw[kk][cp + 8] = u1;
  }
  // stage wt[dd][c] = bf16(Wexp[t, dc*192+dd, h*64+c]) — coalesced rows
  {
    #pragma unroll
    for (int r2 = 0; r2 < 3; ++r2) {
      int idx = r2 * 256 + tid;
      int dd = idx >> 2, cq = (idx & 3) * 16;
      const float* wr =
          Wexp + ((size_t)t * C_ + dc * 192 + dd) * C_ + h * HD_ + cq;
      float4 f0 = *(const float4*)(wr + 0);
      float4 f1 = *(const float4*)(wr + 4);
      float4 f2 = *(const float4*)(wr + 8);
      float4 f3 = *(const float4*)(wr + 12);
      uint4 u0 = make_uint4(pk2(f0.x, f0.y), pk2(f0.z, f0.w),
                            pk2(f1.x, f1.y), pk2(f1.z, f1.w));
      uint4 u1 = make_uint4(pk2(f2.x, f2.y), pk2(f2.z, f2.w),
                            pk2(f3.x, f3.y), pk2(f3.z, f3.w));
      *(uint4*)&wt[dd][cq] = u0;
      *(uint4*)&wt[dd][cq + 8] = u1;
    }
  }
  __syncthreads();

  int lane = tid & 63, wave = tid >> 6;
  int lrow = lane & 15, lk8 = (lane >> 4) * 8, g4 = (lane >> 4) * 4;

  f32x4 acc[12];
  #pragma unroll
  for (int n = 0; n < 12; ++n) acc[n] = (f32x4){0.f, 0.f, 0.f, 0.f};

  #pragma unroll
  for (int ks2 = 0; ks2 < 2; ++ks2) {
    bf16x8 a = *(const bf16x8*)&fw[wave * 16 + lrow][ks2 * 32 + lk8];
    #pragma unroll
    for (int n = 0; n < 12; ++n) {
      bf16x8 bfr = *(const bf16x8*)&wt[n * 16 + lrow][ks2 * 32 + lk8];
      acc[n] = __builtin_amdgcn_mfma_f32_16x16x32_bf16(a, bfr, acc[n], 0, 0, 0);
    }
  }

  // epilogue: D col = lane&15 (d), row = (lane>>4)*4 + q. bf16 stores.
  #pragma unroll
  for (int n = 0; n < 12; ++n) {
    int d = dc * 192 + n * 16 + lrow;
    #pragma unroll
    for (int q = 0; q < 4; ++q) {
      int row = ks * 64 + wave * 16 + g4 + q;
      Y[((size_t)bht * K_ + row) * C_ + d] = f2bf(acc[n][q]);
    }
  }
}

// Combine: out[b, T+m, :] = sum over active th (ascending, deterministic) of
// bf16 Y[bht][sel][:]. Rows with no contributions get zeros.
// grid = B*M/4 blocks, block = 256 (wave per (b,m) row).
__global__ __launch_bounds__(256) void combine_kernel(
    const unsigned short* __restrict__ Y, const int* __restrict__ bucket,
    float* __restrict__ out) {
  int wave = threadIdx.x >> 6, lane = threadIdx.x & 63;
  int bm = blockIdx.x * 4 + wave;
  int b = bm / M_, m = bm % M_;
  const int* bk = bucket + (size_t)bm * 36;
  int v = (lane < 36) ? bk[lane] : 0;
  unsigned long long mask = __ballot(v > 0);
  float a[12] = {0.f};
  while (mask) {
    int th = __ffsll((unsigned long long)mask) - 1;
    mask &= mask - 1;
    int sel = __shfl(v, th) - 1;
    const unsigned short* yr = Y + ((size_t)(b * 36 + th) * K_ + sel) * C_;
    #pragma unroll
    for (int seg = 0; seg < 3; ++seg) {
      uint2 r = *(const uint2*)(yr + seg * 256 + lane * 4);
      a[seg * 4 + 0] += bf2f((unsigned short)(r.x & 0xFFFFu));
      a[seg * 4 + 1] += bf2f((unsigned short)(r.x >> 16));
      a[seg * 4 + 2] += bf2f((unsigned short)(r.y & 0xFFFFu));
      a[seg * 4 + 3] += bf2f((unsigned short)(r.y >> 16));
    }
  }
  float* orow = out + ((size_t)b * TM_ + T_ + m) * C_;
  #pragma unroll
  for (int seg = 0; seg < 3; ++seg) {
    float4 o = make_float4(a[seg * 4 + 0], a[seg * 4 + 1], a[seg * 4 + 2],
                           a[seg * 4 + 3]);
    *(float4*)(orow + seg * 256 + lane * 4) = o;
  }
}

// ---------- launch ----------
extern "C" void kernel_launch(void* const* d_in, const int* in_sizes, int n_in,
                              void* d_out, int out_size, void* d_ws, size_t ws_size,
                              hipStream_t stream) {
  (void)in_sizes; (void)n_in; (void)ws_size; (void)out_size;
  const float* x = (const float*)d_in[0];
  const float* Wq = (const float*)d_in[1];
  const float* bq = (const float*)d_in[2];
  const float* Wkv = (const float*)d_in[3];
  const float* bkv = (const float*)d_in[4];
  const float* Wexp = (const float*)d_in[5];
  float* out = (float*)d_out;

  // workspace layout (~61.6 MiB; scp and Ybf alias — disjoint lifetimes)
  char* ws = (char*)d_ws;
  float* qbuf = (float*)ws;                          //        36,864 B
  float* atbuf = (float*)(ws + 36864);               //        36,864 B
  int* ibuf = (int*)(ws + 73728);                    //       147,456 B
  float* wbuf = (float*)(ws + 221184);               //       147,456 B
  float* sprjT = (float*)(ws + 368640);              //       442,368 B
  float* qbb = (float*)(ws + 811008);                //     1,024 B pad
  float* wfp = (float*)(ws + 812032);                //     1,769,472 B
  int* bucket = (int*)(ws + 2581504);                //     2,359,296 B
  float* scp = (float*)(ws + 4940800);               //    28,311,552 B (12 partials)
  unsigned short* Ybf = (unsigned short*)(ws + 4940800); // 56,623,104 B (alias)
  // end: 61,563,904 B

  hipMemsetAsync(bucket, 0, (size_t)B_ * M_ * 36 * 4, stream);
  q_kernel<<<dim3(T_, 12), 256, 0, stream>>>(x, Wq, bq, qbuf);
  sprj_kernel<<<NBLK_, 256, 0, stream>>>(qbuf, Wkv, bkv, sprjT, qbb);
  score_kernel<<<dim3(B_, 16, 12), 256, 0, stream>>>(x, sprjT, scp);
  topk_kernel<<<NBLK_, 256, 0, stream>>>(scp, qbb, ibuf, wbuf);
  bucket_build<<<NBLK_, 256, 0, stream>>>(ibuf, bucket);
  wfeat_kernel<<<dim3(NBLK_, 4, 3), 256, 0, stream>>>(x, ibuf, wbuf, wfp);
  attn_token_kernel<<<NBLK_, 256, 0, stream>>>(wfp, Wkv, bkv, atbuf);
  token_out<<<dim3(T_, 12), 256, 0, stream>>>(atbuf, Wexp, out);
  scatter_mfma<<<dim3(36, 16, 4), 256, 0, stream>>>(x, Wexp, ibuf, wbuf, Ybf);
  combine_kernel<<<B_ * M_ / 4, 256, 0, stream>>>(Ybf, bucket, out);
}

// Round 13
// 141.311 us; speedup vs baseline: 1.5904x; 1.0160x over previous
//
#include <hip/hip_runtime.h>
#include <hip/hip_bf16.h>

#define B_ 4
#define T_ 3
#define M_ 4096
#define C_ 768
#define H_ 12
#define K_ 256
#define HD_ 64
#define TM_ 4099      // T_ + M_
#define SCALE_ 0.125f // HD^-0.5
#define NBLK_ 144     // B*H*T, blk = b*36 + h*3 + t, th = h*3+t

typedef __attribute__((ext_vector_type(8))) short bf16x8;
typedef __attribute__((ext_vector_type(4))) float f32x4;

// order-preserving float->uint key (larger float -> larger key)
__device__ __forceinline__ unsigned keyf(float f) {
  unsigned u = __float_as_uint(f);
  return (u & 0x80000000u) ? ~u : (u | 0x80000000u);
}

__device__ __forceinline__ unsigned short f2bf(float f) { // RNE
  unsigned u = __float_as_uint(f);
  unsigned r = (u + 0x7FFFu + ((u >> 16) & 1u)) >> 16;
  return (unsigned short)r;
}
__device__ __forceinline__ float bf2f(unsigned short u) {
  return __uint_as_float(((unsigned)u) << 16);
}
__device__ __forceinline__ unsigned pk2(float a, float b) {
  return (unsigned)f2bf(a) | ((unsigned)f2bf(b) << 16);
}

// block exclusive scan over 256 threads: wave shfl scan + 4-word combine.
__device__ __forceinline__ int block_excl_scan256(int v, int tid, int* sbuf) {
  int lane = tid & 63, wid = tid >> 6;
  int x = v;
  #pragma unroll
  for (int off = 1; off < 64; off <<= 1) {
    int y = __shfl_up(x, off, 64);
    if (lane >= off) x += y;
  }
  if (lane == 63) sbuf[wid] = x;
  __syncthreads();
  int base = 0;
  #pragma unroll
  for (int w = 0; w < 3; ++w) base += (w < wid) ? sbuf[w] : 0;
  __syncthreads(); // safe reuse of sbuf by next call
  return base + x - v;
}

// ---------- kernels ----------

// zero the bucket (2.36 MB) — replaces runtime fillBufferAligned (39us -> ~1us)
// grid = 576, block = 256, uint4 stores.
__global__ __launch_bounds__(256) void zero_bucket(uint4* __restrict__ p) {
  p[blockIdx.x * 256 + threadIdx.x] = make_uint4(0u, 0u, 0u, 0u);
}

// q[b,t,d] = sum_c x[b,t,c] * Wq[t,d,c] + bq[t,d]
// grid = (T, 12 dchunks of 64), block = 256. Reads Wq once (4 b per block).
__global__ __launch_bounds__(256) void q_kernel(const float* __restrict__ x,
                                                const float* __restrict__ Wq,
                                                const float* __restrict__ bq,
                                                float* __restrict__ qbuf) {
  int t = blockIdx.x;
  int d0 = blockIdx.y * 64;
  int tid = threadIdx.x;
  __shared__ float ar[B_][C_];
  for (int i = tid; i < B_ * C_; i += 256) {
    int bb = i / C_, c = i % C_;
    ar[bb][c] = x[((size_t)(bb * TM_ + t)) * C_ + c];
  }
  __syncthreads();
  int grp = tid >> 4, ln = tid & 15;
  #pragma unroll
  for (int j = 0; j < 4; ++j) {
    int d = d0 + grp * 4 + j;
    const float4* wr = (const float4*)(Wq + ((size_t)t * C_ + d) * C_);
    float a0 = 0.f, a1 = 0.f, a2 = 0.f, a3 = 0.f;
    #pragma unroll
    for (int it = 0; it < 12; ++it) {
      float4 w4 = wr[ln + 16 * it];
      const float4 x0 = *(const float4*)&ar[0][(ln + 16 * it) * 4];
      const float4 x1 = *(const float4*)&ar[1][(ln + 16 * it) * 4];
      const float4 x2 = *(const float4*)&ar[2][(ln + 16 * it) * 4];
      const float4 x3 = *(const float4*)&ar[3][(ln + 16 * it) * 4];
      a0 += w4.x * x0.x + w4.y * x0.y + w4.z * x0.z + w4.w * x0.w;
      a1 += w4.x * x1.x + w4.y * x1.y + w4.z * x1.z + w4.w * x1.w;
      a2 += w4.x * x2.x + w4.y * x2.y + w4.z * x2.z + w4.w * x2.w;
      a3 += w4.x * x3.x + w4.y * x3.y + w4.z * x3.z + w4.w * x3.w;
    }
    #pragma unroll
    for (int off = 1; off < 16; off <<= 1) {
      a0 += __shfl_xor(a0, off, 16);
      a1 += __shfl_xor(a1, off, 16);
      a2 += __shfl_xor(a2, off, 16);
      a3 += __shfl_xor(a3, off, 16);
    }
    if (ln == 0) {
      float bqv = bq[t * C_ + d];
      qbuf[(size_t)(0 * T_ + t) * C_ + d] = a0 + bqv;
      qbuf[(size_t)(1 * T_ + t) * C_ + d] = a1 + bqv;
      qbuf[(size_t)(2 * T_ + t) * C_ + d] = a2 + bqv;
      qbuf[(size_t)(3 * T_ + t) * C_ + d] = a3 + bqv;
    }
  }
}

// sprjT[(b*768+c)*36 + j] = sum_{i<64} q[b,t,h*64+i] * Wkv[h*64+i, c]
// qbb[blk] = sum_{i<64} q[b,t,h*64+i] * bkv[h*64+i]
__global__ __launch_bounds__(256) void sprj_kernel(const float* __restrict__ qbuf,
                                                   const float* __restrict__ Wkv,
                                                   const float* __restrict__ bkv,
                                                   float* __restrict__ sprjT,
                                                   float* __restrict__ qbb) {
  int blk = blockIdx.x;
  int j = blk % 36;
  int b = blk / 36;
  int t = j % T_;
  int h = j / T_;
  int tid = threadIdx.x;
  __shared__ float qs[HD_];
  if (tid < HD_) qs[tid] = qbuf[((size_t)(b * T_ + t)) * C_ + h * HD_ + tid];
  __syncthreads();
  if (tid == 0) {
    float s = 0.f;
    for (int i = 0; i < HD_; ++i) s += qs[i] * bkv[h * HD_ + i];
    qbb[blk] = s;
  }
  float a0 = 0.f, a1 = 0.f, a2 = 0.f;
  for (int i = 0; i < HD_; ++i) {
    const float* wr = Wkv + ((size_t)(h * HD_ + i)) * C_;
    float qi = qs[i];
    a0 += qi * wr[tid];
    a1 += qi * wr[tid + 256];
    a2 += qi * wr[tid + 512];
  }
  sprjT[((size_t)b * C_ + tid) * 36 + j] = a0;
  sprjT[((size_t)b * C_ + tid + 256) * 36 + j] = a1;
  sprjT[((size_t)b * C_ + tid + 512) * 36 + j] = a2;
}

// score partials: scp[(cc*144 + b*36 + j)*M + m] = partial dot over 64 c's.
// grid = (B, 16 m-tiles of 256, 12 c-chunks of 64), block = 256.
__global__ __launch_bounds__(256) void score_kernel(const float* __restrict__ x,
                                                    const float* __restrict__ sprjT,
                                                    float* __restrict__ scp) {
  int b = blockIdx.x;
  int m0 = blockIdx.y * 256;
  int cc = blockIdx.z;
  int tid = threadIdx.x;

  __shared__ float fl[32][256]; // [c][m]

  float acc[36];
  #pragma unroll
  for (int j = 0; j < 36; ++j) acc[j] = 0.f;

  const float* fr0 = x + ((size_t)(b * TM_ + T_ + m0 + tid)) * C_ + cc * 64;

  for (int kc = 0; kc < 2; ++kc) {
    float4 v[8];
    const float4* fr = (const float4*)(fr0 + kc * 32);
    #pragma unroll
    for (int i = 0; i < 8; ++i) v[i] = fr[i];
    __syncthreads();
    #pragma unroll
    for (int i = 0; i < 8; ++i) {
      fl[i * 4 + 0][tid] = v[i].x;
      fl[i * 4 + 1][tid] = v[i].y;
      fl[i * 4 + 2][tid] = v[i].z;
      fl[i * 4 + 3][tid] = v[i].w;
    }
    __syncthreads();
    const float* sp = sprjT + ((size_t)b * C_ + cc * 64 + kc * 32) * 36;
    #pragma unroll 4
    for (int k = 0; k < 32; ++k) {
      float f = fl[k][tid];
      const float* sr = sp + k * 36; // uniform -> s_load
      #pragma unroll
      for (int j = 0; j < 36; ++j) acc[j] += f * sr[j];
    }
  }
  float* op = scp + ((size_t)cc * NBLK_ + (size_t)b * 36) * M_ + m0 + tid;
  #pragma unroll
  for (int j = 0; j < 36; ++j) op[(size_t)j * M_] = acc[j];
}

// Fused score-reduce + exact top-K (radix select, index-ordered ties =
// lax.top_k) + softmax + bucket scatter. grid = 144, block = 256.
__global__ __launch_bounds__(256) void topk_kernel(const float* __restrict__ scp,
                                                   const float* __restrict__ qbb,
                                                   int* __restrict__ ibuf,
                                                   float* __restrict__ wbuf,
                                                   int* __restrict__ bucket) {
  int blk = blockIdx.x;
  int tid = threadIdx.x;

  __shared__ float sc[M_];
  __shared__ unsigned hist[256];
  __shared__ int sbuf[4];
  __shared__ int selm[K_];
  __shared__ float redf[4];
  __shared__ int sh_bin, sh_rem;

  // reduce 12 c-chunk partials (ascending cc, deterministic) + scale
  float qb = qbb[blk];
  for (int i = tid; i < M_ / 4; i += 256) {
    float4 s = make_float4(qb, qb, qb, qb);
    #pragma unroll
    for (int cc = 0; cc < 12; ++cc) {
      float4 a = *(const float4*)&scp[((size_t)cc * NBLK_ + blk) * M_ + i * 4];
      s.x += a.x; s.y += a.y; s.z += a.z; s.w += a.w;
    }
    *(float4*)&sc[i * 4] =
        make_float4(s.x * SCALE_, s.y * SCALE_, s.z * SCALE_, s.w * SCALE_);
  }
  __syncthreads();

  // ---- radix select: find K-th largest key ----
  unsigned prefix = 0;
  int remaining = K_;
  for (int shift = 24; shift >= 0; shift -= 8) {
    hist[tid] = 0;
    __syncthreads();
    unsigned pmask = (shift == 24) ? 0u : (0xFFFFFFFFu << (shift + 8));
    #pragma unroll 4
    for (int i = 0; i < 16; ++i) {
      unsigned k = keyf(sc[tid * 16 + i]);
      if ((k & pmask) == prefix) atomicAdd(&hist[(k >> shift) & 255u], 1u);
    }
    __syncthreads();
    int bin = 255 - tid;
    int v = (int)hist[bin];
    int cex = block_excl_scan256(v, tid, sbuf);
    if (cex < remaining && cex + v >= remaining) {
      sh_bin = bin;
      sh_rem = remaining - cex;
    }
    __syncthreads();
    prefix |= ((unsigned)sh_bin) << shift;
    remaining = sh_rem;
    __syncthreads();
  }
  const unsigned tau = prefix;
  const int r = remaining;      // # of ==tau entries to keep (lowest indices)
  const int cgt = K_ - r;       // # of >tau entries

  // ---- compact selection in ascending-index order (deterministic) ----
  int base = tid * 16;
  int myCnt = 0, myTie = 0;
  #pragma unroll
  for (int i = 0; i < 16; i++) {
    unsigned k = keyf(sc[base + i]);
    myCnt += (k > tau);
    myTie += (k == tau);
  }
  int offs = block_excl_scan256(myCnt, tid, sbuf);
  int toffs = block_excl_scan256(myTie, tid, sbuf);
  for (int i = 0; i < 16; i++) {
    int m = base + i;
    unsigned k = keyf(sc[m]);
    if (k > tau) {
      selm[offs++] = m;
    } else if (k == tau) {
      if (toffs < r) selm[cgt + toffs] = m;
      toffs++;
    }
  }
  __syncthreads();

  // ---- softmax over the K selected (wave reduce + 4-word combine) ----
  int m = selm[tid];
  float val = sc[m];
  float mx = val;
  #pragma unroll
  for (int off = 32; off > 0; off >>= 1) mx = fmaxf(mx, __shfl_xor(mx, off, 64));
  if ((tid & 63) == 0) redf[tid >> 6] = mx;
  __syncthreads();
  mx = fmaxf(fmaxf(redf[0], redf[1]), fmaxf(redf[2], redf[3]));
  float e = expf(val - mx);
  float sm = e;
  #pragma unroll
  for (int off = 32; off > 0; off >>= 1) sm += __shfl_xor(sm, off, 64);
  __syncthreads();
  if ((tid & 63) == 0) redf[tid >> 6] = sm;
  __syncthreads();
  sm = redf[0] + redf[1] + redf[2] + redf[3];
  ibuf[(size_t)blk * K_ + tid] = m;
  wbuf[(size_t)blk * K_ + tid] = e / sm;
  // fused bucket scatter: per (b,m) each th writes at most one slot -> no
  // atomics, deterministic.
  bucket[((size_t)(blk / 36) * M_ + m) * 36 + (blk % 36)] = tid + 1;
}

// wfp[blk*4+kc][c] = sum_{k in chunk} w_k * feat[m_k, c]
// grid = (144, 4, 3 c-segments), block = 256
__global__ __launch_bounds__(256) void wfeat_kernel(const float* __restrict__ x,
                                                    const int* __restrict__ ibuf,
                                                    const float* __restrict__ wbuf,
                                                    float* __restrict__ wfp) {
  int blk = blockIdx.x, kc = blockIdx.y, cseg = blockIdx.z;
  int b = blk / 36;
  int tid = threadIdx.x;
  __shared__ int ml[64];
  __shared__ float wl[64];
  if (tid < 64) {
    ml[tid] = ibuf[(size_t)blk * K_ + kc * 64 + tid];
    wl[tid] = wbuf[(size_t)blk * K_ + kc * 64 + tid];
  }
  __syncthreads();
  int c = cseg * 256 + tid;
  const float* fbase = x + ((size_t)b * TM_ + T_) * C_ + c;
  float a = 0.f;
  #pragma unroll 4
  for (int kk = 0; kk < 64; ++kk) {
    a += wl[kk] * fbase[(size_t)ml[kk] * C_];
  }
  wfp[((size_t)blk * 4 + kc) * C_ + c] = a;
}

// attn_token[b,t,h*64+rr] = (sum_kc wfp) . Wv[row] + bv[row]; grid = 144
__global__ __launch_bounds__(256) void attn_token_kernel(
    const float* __restrict__ wfp, const float* __restrict__ Wkv,
    const float* __restrict__ bkv, float* __restrict__ atbuf) {
  int blk = blockIdx.x;
  int t = blk % T_;
  int h = (blk / T_) % H_;
  int b = blk / (T_ * H_);
  int tid = threadIdx.x;
  __shared__ float wfeat[C_];
  const float* p0 = wfp + ((size_t)blk * 4) * C_;
  #pragma unroll
  for (int j = 0; j < 3; ++j) {
    int c = tid + j * 256;
    wfeat[c] = p0[c] + p0[C_ + c] + p0[2 * C_ + c] + p0[3 * C_ + c];
  }
  __syncthreads();
  int grp = tid >> 4, ln = tid & 15;
  for (int rr = grp; rr < HD_; rr += 16) {
    const float4* wr = (const float4*)(Wkv + ((size_t)(C_ + h * HD_ + rr)) * C_);
    float acc = 0.f;
    #pragma unroll
    for (int it = 0; it < 12; ++it) {
      float4 wv = wr[ln + it * 16];
      const float4 fv = *(const float4*)&wfeat[(ln + it * 16) * 4];
      acc += wv.x * fv.x + wv.y * fv.y + wv.z * fv.z + wv.w * fv.w;
    }
    acc += __shfl_xor(acc, 1, 16);
    acc += __shfl_xor(acc, 2, 16);
    acc += __shfl_xor(acc, 4, 16);
    acc += __shfl_xor(acc, 8, 16);
    if (ln == 0)
      atbuf[((size_t)(b * T_ + t)) * C_ + h * HD_ + rr] =
          acc + bkv[C_ + h * HD_ + rr];
  }
}

// token_output[b,t,d] = sum_c attn_token[b,t,c] * Wexp[t,d,c]
// grid = (T, 12 dchunks of 64), block 256. Fully writes task rows of out.
__global__ __launch_bounds__(256) void token_out(const float* __restrict__ atbuf,
                                                 const float* __restrict__ Wexp,
                                                 float* __restrict__ out) {
  int t = blockIdx.x;
  int d0 = blockIdx.y * 64;
  int tid = threadIdx.x;
  __shared__ float ar[B_][C_];
  for (int i = tid; i < B_ * C_; i += 256) {
    int bb = i / C_, c = i % C_;
    ar[bb][c] = atbuf[((size_t)(bb * T_ + t)) * C_ + c];
  }
  __syncthreads();
  int grp = tid >> 4, ln = tid & 15;
  #pragma unroll
  for (int j = 0; j < 4; ++j) {
    int d = d0 + grp * 4 + j;
    const float4* wr = (const float4*)(Wexp + ((size_t)t * C_ + d) * C_);
    float a0 = 0.f, a1 = 0.f, a2 = 0.f, a3 = 0.f;
    #pragma unroll
    for (int it = 0; it < 12; ++it) {
      float4 w4 = wr[ln + 16 * it];
      const float4 x0 = *(const float4*)&ar[0][(ln + 16 * it) * 4];
      const float4 x1 = *(const float4*)&ar[1][(ln + 16 * it) * 4];
      const float4 x2 = *(const float4*)&ar[2][(ln + 16 * it) * 4];
      const float4 x3 = *(const float4*)&ar[3][(ln + 16 * it) * 4];
      a0 += w4.x * x0.x + w4.y * x0.y + w4.z * x0.z + w4.w * x0.w;
      a1 += w4.x * x1.x + w4.y * x1.y + w4.z * x1.z + w4.w * x1.w;
      a2 += w4.x * x2.x + w4.y * x2.y + w4.z * x2.z + w4.w * x2.w;
      a3 += w4.x * x3.x + w4.y * x3.y + w4.z * x3.z + w4.w * x3.w;
    }
    #pragma unroll
    for (int off = 1; off < 16; off <<= 1) {
      a0 += __shfl_xor(a0, off, 16);
      a1 += __shfl_xor(a1, off, 16);
      a2 += __shfl_xor(a2, off, 16);
      a3 += __shfl_xor(a3, off, 16);
    }
    if (ln == 0) {
      out[((size_t)0 * TM_ + t) * C_ + d] = a0;
      out[((size_t)1 * TM_ + t) * C_ + d] = a1;
      out[((size_t)2 * TM_ + t) * C_ + d] = a2;
      out[((size_t)3 * TM_ + t) * C_ + d] = a3;
    }
  }
}

// All-b MFMA GEMM into dense bf16 Y (no atomics):
//   Y[bht][sel][d] = bf16( w_sel * feat[b,m_sel,h64] @ Wexp[t,:,h64]^T )
// grid = (36 th, 16 = b*4+ks, 4 dc), block = 256 (4 waves).
__global__ __launch_bounds__(256) void scatter_mfma(
    const float* __restrict__ x, const float* __restrict__ Wexp,
    const int* __restrict__ ibuf, const float* __restrict__ wbuf,
    unsigned short* __restrict__ Y) {
  int th = blockIdx.x;
  int h = th / T_, t = th % T_;
  int b = blockIdx.y >> 2, ks = blockIdx.y & 3;
  int dc = blockIdx.z;
  int bht = b * 36 + th;
  int tid = threadIdx.x;

  __shared__ unsigned short fw[64][72];
  __shared__ unsigned short wt[192][72];

  // stage fw (bf16 of w * feat slice): thread = (kk, 16-c chunk)
  {
    int kk = tid >> 2, cp = (tid & 3) * 16;
    int sel = ks * 64 + kk;
    int m = ibuf[(size_t)bht * K_ + sel];
    float w = wbuf[(size_t)bht * K_ + sel];
    const float* fr = x + ((size_t)(b * TM_) + T_ + m) * C_ + h * HD_ + cp;
    float4 f0 = *(const float4*)(fr + 0);
    float4 f1 = *(const float4*)(fr + 4);
    float4 f2 = *(const float4*)(fr + 8);
    float4 f3 = *(const float4*)(fr + 12);
    uint4 u0 = make_uint4(pk2(f0.x * w, f0.y * w), pk2(f0.z * w, f0.w * w),
                          pk2(f1.x * w, f1.y * w), pk2(f1.z * w, f1.w * w));
    uint4 u1 = make_uint4(pk2(f2.x * w, f2.y * w), pk2(f2.z * w, f2.w * w),
                          pk2(f3.x * w, f3.y * w), pk2(f3.z * w, f3.w * w));
    *(uint4*)&fw[kk][cp] = u0;
    *(uint4*)&fw[kk][cp + 8] = u1;
  }
  // stage wt[dd][c] = bf16(Wexp[t, dc*192+dd, h*64+c]) — coalesced rows
  {
    #pragma unroll
    for (int r2 = 0; r2 < 3; ++r2) {
      int idx = r2 * 256 + tid;
      int dd = idx >> 2, cq = (idx & 3) * 16;
      const float* wr =
          Wexp + ((size_t)t * C_ + dc * 192 + dd) * C_ + h * HD_ + cq;
      float4 f0 = *(const float4*)(wr + 0);
      float4 f1 = *(const float4*)(wr + 4);
      float4 f2 = *(const float4*)(wr + 8);
      float4 f3 = *(const float4*)(wr + 12);
      uint4 u0 = make_uint4(pk2(f0.x, f0.y), pk2(f0.z, f0.w),
                            pk2(f1.x, f1.y), pk2(f1.z, f1.w));
      uint4 u1 = make_uint4(pk2(f2.x, f2.y), pk2(f2.z, f2.w),
                            pk2(f3.x, f3.y), pk2(f3.z, f3.w));
      *(uint4*)&wt[dd][cq] = u0;
      *(uint4*)&wt[dd][cq + 8] = u1;
    }
  }
  __syncthreads();

  int lane = tid & 63, wave = tid >> 6;
  int lrow = lane & 15, lk8 = (lane >> 4) * 8, g4 = (lane >> 4) * 4;

  f32x4 acc[12];
  #pragma unroll
  for (int n = 0; n < 12; ++n) acc[n] = (f32x4){0.f, 0.f, 0.f, 0.f};

  #pragma unroll
  for (int ks2 = 0; ks2 < 2; ++ks2) {
    bf16x8 a = *(const bf16x8*)&fw[wave * 16 + lrow][ks2 * 32 + lk8];
    #pragma unroll
    for (int n = 0; n < 12; ++n) {
      bf16x8 bfr = *(const bf16x8*)&wt[n * 16 + lrow][ks2 * 32 + lk8];
      acc[n] = __builtin_amdgcn_mfma_f32_16x16x32_bf16(a, bfr, acc[n], 0, 0, 0);
    }
  }

  // epilogue: D col = lane&15 (d), row = (lane>>4)*4 + q. bf16 stores.
  #pragma unroll
  for (int n = 0; n < 12; ++n) {
    int d = dc * 192 + n * 16 + lrow;
    #pragma unroll
    for (int q = 0; q < 4; ++q) {
      int row = ks * 64 + wave * 16 + g4 + q;
      Y[((size_t)bht * K_ + row) * C_ + d] = f2bf(acc[n][q]);
    }
  }
}

// Combine: out[b, T+m, :] = sum over active th (ascending, deterministic) of
// bf16 Y[bht][sel][:]. Rows with no contributions get zeros.
// grid = B*M/4 blocks, block = 256 (wave per (b,m) row).
__global__ __launch_bounds__(256) void combine_kernel(
    const unsigned short* __restrict__ Y, const int* __restrict__ bucket,
    float* __restrict__ out) {
  int wave = threadIdx.x >> 6, lane = threadIdx.x & 63;
  int bm = blockIdx.x * 4 + wave;
  int b = bm / M_, m = bm % M_;
  const int* bk = bucket + (size_t)bm * 36;
  int v = (lane < 36) ? bk[lane] : 0;
  unsigned long long mask = __ballot(v > 0);
  float a[12] = {0.f};
  while (mask) {
    int th = __ffsll((unsigned long long)mask) - 1;
    mask &= mask - 1;
    int sel = __shfl(v, th) - 1;
    const unsigned short* yr = Y + ((size_t)(b * 36 + th) * K_ + sel) * C_;
    #pragma unroll
    for (int seg = 0; seg < 3; ++seg) {
      uint2 r = *(const uint2*)(yr + seg * 256 + lane * 4);
      a[seg * 4 + 0] += bf2f((unsigned short)(r.x & 0xFFFFu));
      a[seg * 4 + 1] += bf2f((unsigned short)(r.x >> 16));
      a[seg * 4 + 2] += bf2f((unsigned short)(r.y & 0xFFFFu));
      a[seg * 4 + 3] += bf2f((unsigned short)(r.y >> 16));
    }
  }
  float* orow = out + ((size_t)b * TM_ + T_ + m) * C_;
  #pragma unroll
  for (int seg = 0; seg < 3; ++seg) {
    float4 o = make_float4(a[seg * 4 + 0], a[seg * 4 + 1], a[seg * 4 + 2],
                           a[seg * 4 + 3]);
    *(float4*)(orow + seg * 256 + lane * 4) = o;
  }
}

// ---------- launch ----------
extern "C" void kernel_launch(void* const* d_in, const int* in_sizes, int n_in,
                              void* d_out, int out_size, void* d_ws, size_t ws_size,
                              hipStream_t stream) {
  (void)in_sizes; (void)n_in; (void)ws_size; (void)out_size;
  const float* x = (const float*)d_in[0];
  const float* Wq = (const float*)d_in[1];
  const float* bq = (const float*)d_in[2];
  const float* Wkv = (const float*)d_in[3];
  const float* bkv = (const float*)d_in[4];
  const float* Wexp = (const float*)d_in[5];
  float* out = (float*)d_out;

  // workspace layout (~61.6 MiB; scp and Ybf alias — disjoint lifetimes)
  char* ws = (char*)d_ws;
  float* qbuf = (float*)ws;                          //        36,864 B
  float* atbuf = (float*)(ws + 36864);               //        36,864 B
  int* ibuf = (int*)(ws + 73728);                    //       147,456 B
  float* wbuf = (float*)(ws + 221184);               //       147,456 B
  float* sprjT = (float*)(ws + 368640);              //       442,368 B
  float* qbb = (float*)(ws + 811008);                //     1,024 B pad
  float* wfp = (float*)(ws + 812032);                //     1,769,472 B
  int* bucket = (int*)(ws + 2581504);                //     2,359,296 B
  float* scp = (float*)(ws + 4940800);               //    28,311,552 B (12 partials)
  unsigned short* Ybf = (unsigned short*)(ws + 4940800); // 56,623,104 B (alias)
  // end: 61,563,904 B

  zero_bucket<<<576, 256, 0, stream>>>((uint4*)bucket);
  q_kernel<<<dim3(T_, 12), 256, 0, stream>>>(x, Wq, bq, qbuf);
  sprj_kernel<<<NBLK_, 256, 0, stream>>>(qbuf, Wkv, bkv, sprjT, qbb);
  score_kernel<<<dim3(B_, 16, 12), 256, 0, stream>>>(x, sprjT, scp);
  topk_kernel<<<NBLK_, 256, 0, stream>>>(scp, qbb, ibuf, wbuf, bucket);
  wfeat_kernel<<<dim3(NBLK_, 4, 3), 256, 0, stream>>>(x, ibuf, wbuf, wfp);
  attn_token_kernel<<<NBLK_, 256, 0, stream>>>(wfp, Wkv, bkv, atbuf);
  token_out<<<dim3(T_, 12), 256, 0, stream>>>(atbuf, Wexp, out);
  scatter_mfma<<<dim3(36, 16, 4), 256, 0, stream>>>(x, Wexp, ibuf, wbuf, Ybf);
  combine_kernel<<<B_ * M_ / 4, 256, 0, stream>>>(Ybf, bucket, out);
}

// Round 14
// 138.984 us; speedup vs baseline: 1.6170x; 1.0167x over previous
//
#include <hip/hip_runtime.h>
#include <hip/hip_bf16.h>

#define B_ 4
#define T_ 3
#define M_ 4096
#define C_ 768
#define H_ 12
#define K_ 256
#define HD_ 64
#define TM_ 4099      // T_ + M_
#define SCALE_ 0.125f // HD^-0.5
#define NBLK_ 144     // B*H*T, blk = b*36 + h*3 + t, th = h*3+t

typedef __attribute__((ext_vector_type(8))) short bf16x8;
typedef __attribute__((ext_vector_type(4))) float f32x4;

// order-preserving float->uint key (larger float -> larger key)
__device__ __forceinline__ unsigned keyf(float f) {
  unsigned u = __float_as_uint(f);
  return (u & 0x80000000u) ? ~u : (u | 0x80000000u);
}

__device__ __forceinline__ unsigned short f2bf(float f) { // RNE
  unsigned u = __float_as_uint(f);
  unsigned r = (u + 0x7FFFu + ((u >> 16) & 1u)) >> 16;
  return (unsigned short)r;
}
__device__ __forceinline__ float bf2f(unsigned short u) {
  return __uint_as_float(((unsigned)u) << 16);
}
__device__ __forceinline__ unsigned pk2(float a, float b) {
  return (unsigned)f2bf(a) | ((unsigned)f2bf(b) << 16);
}

// block exclusive scan over 256 threads: wave shfl scan + 4-word combine.
__device__ __forceinline__ int block_excl_scan256(int v, int tid, int* sbuf) {
  int lane = tid & 63, wid = tid >> 6;
  int x = v;
  #pragma unroll
  for (int off = 1; off < 64; off <<= 1) {
    int y = __shfl_up(x, off, 64);
    if (lane >= off) x += y;
  }
  if (lane == 63) sbuf[wid] = x;
  __syncthreads();
  int base = 0;
  #pragma unroll
  for (int w = 0; w < 3; ++w) base += (w < wid) ? sbuf[w] : 0;
  __syncthreads(); // safe reuse of sbuf by next call
  return base + x - v;
}

// ---------- kernels ----------

// q[b,t,d] = sum_c x[b,t,c] * Wq[t,d,c] + bq[t,d]
// grid = (T, 12 dchunks of 64), block = 256. Reads Wq once (4 b per block).
__global__ __launch_bounds__(256) void q_kernel(const float* __restrict__ x,
                                                const float* __restrict__ Wq,
                                                const float* __restrict__ bq,
                                                float* __restrict__ qbuf) {
  int t = blockIdx.x;
  int d0 = blockIdx.y * 64;
  int tid = threadIdx.x;
  __shared__ float ar[B_][C_];
  for (int i = tid; i < B_ * C_; i += 256) {
    int bb = i / C_, c = i % C_;
    ar[bb][c] = x[((size_t)(bb * TM_ + t)) * C_ + c];
  }
  __syncthreads();
  int grp = tid >> 4, ln = tid & 15;
  #pragma unroll
  for (int j = 0; j < 4; ++j) {
    int d = d0 + grp * 4 + j;
    const float4* wr = (const float4*)(Wq + ((size_t)t * C_ + d) * C_);
    float a0 = 0.f, a1 = 0.f, a2 = 0.f, a3 = 0.f;
    #pragma unroll
    for (int it = 0; it < 12; ++it) {
      float4 w4 = wr[ln + 16 * it];
      const float4 x0 = *(const float4*)&ar[0][(ln + 16 * it) * 4];
      const float4 x1 = *(const float4*)&ar[1][(ln + 16 * it) * 4];
      const float4 x2 = *(const float4*)&ar[2][(ln + 16 * it) * 4];
      const float4 x3 = *(const float4*)&ar[3][(ln + 16 * it) * 4];
      a0 += w4.x * x0.x + w4.y * x0.y + w4.z * x0.z + w4.w * x0.w;
      a1 += w4.x * x1.x + w4.y * x1.y + w4.z * x1.z + w4.w * x1.w;
      a2 += w4.x * x2.x + w4.y * x2.y + w4.z * x2.z + w4.w * x2.w;
      a3 += w4.x * x3.x + w4.y * x3.y + w4.z * x3.z + w4.w * x3.w;
    }
    #pragma unroll
    for (int off = 1; off < 16; off <<= 1) {
      a0 += __shfl_xor(a0, off, 16);
      a1 += __shfl_xor(a1, off, 16);
      a2 += __shfl_xor(a2, off, 16);
      a3 += __shfl_xor(a3, off, 16);
    }
    if (ln == 0) {
      float bqv = bq[t * C_ + d];
      qbuf[(size_t)(0 * T_ + t) * C_ + d] = a0 + bqv;
      qbuf[(size_t)(1 * T_ + t) * C_ + d] = a1 + bqv;
      qbuf[(size_t)(2 * T_ + t) * C_ + d] = a2 + bqv;
      qbuf[(size_t)(3 * T_ + t) * C_ + d] = a3 + bqv;
    }
  }
}

// sprjT[(b*768+c)*36 + j] = sum_{i<64} q[b,t,h*64+i] * Wkv[h*64+i, c]
// qbb[blk] = sum_{i<64} q[b,t,h*64+i] * bkv[h*64+i]
// Also zeros the bucket (coalesced, 4 uint4/thread) — replaces zero_bucket.
__global__ __launch_bounds__(256) void sprj_kernel(const float* __restrict__ qbuf,
                                                   const float* __restrict__ Wkv,
                                                   const float* __restrict__ bkv,
                                                   float* __restrict__ sprjT,
                                                   float* __restrict__ qbb,
                                                   uint4* __restrict__ bucketz) {
  int blk = blockIdx.x;
  int j = blk % 36;
  int b = blk / 36;
  int t = j % T_;
  int h = j / T_;
  int tid = threadIdx.x;
  // zero bucket: 147,456 uint4 total, 144 blocks * 256 thr * 4
  {
    uint4 z = make_uint4(0u, 0u, 0u, 0u);
    int base = blk * 256 + tid;
    #pragma unroll
    for (int i = 0; i < 4; ++i) bucketz[i * 36864 + base] = z;
  }
  __shared__ float qs[HD_];
  if (tid < HD_) qs[tid] = qbuf[((size_t)(b * T_ + t)) * C_ + h * HD_ + tid];
  __syncthreads();
  if (tid == 0) {
    float s = 0.f;
    for (int i = 0; i < HD_; ++i) s += qs[i] * bkv[h * HD_ + i];
    qbb[blk] = s;
  }
  float a0 = 0.f, a1 = 0.f, a2 = 0.f;
  for (int i = 0; i < HD_; ++i) {
    const float* wr = Wkv + ((size_t)(h * HD_ + i)) * C_;
    float qi = qs[i];
    a0 += qi * wr[tid];
    a1 += qi * wr[tid + 256];
    a2 += qi * wr[tid + 512];
  }
  sprjT[((size_t)b * C_ + tid) * 36 + j] = a0;
  sprjT[((size_t)b * C_ + tid + 256) * 36 + j] = a1;
  sprjT[((size_t)b * C_ + tid + 512) * 36 + j] = a2;
}

// score partials: scp[(cc*144 + b*36 + j)*M + m] = partial dot over 64 c's.
// grid = (B, 16 m-tiles of 256, 12 c-chunks of 64), block = 256.
__global__ __launch_bounds__(256) void score_kernel(const float* __restrict__ x,
                                                    const float* __restrict__ sprjT,
                                                    float* __restrict__ scp) {
  int b = blockIdx.x;
  int m0 = blockIdx.y * 256;
  int cc = blockIdx.z;
  int tid = threadIdx.x;

  __shared__ float fl[32][256]; // [c][m]

  float acc[36];
  #pragma unroll
  for (int j = 0; j < 36; ++j) acc[j] = 0.f;

  const float* fr0 = x + ((size_t)(b * TM_ + T_ + m0 + tid)) * C_ + cc * 64;

  for (int kc = 0; kc < 2; ++kc) {
    float4 v[8];
    const float4* fr = (const float4*)(fr0 + kc * 32);
    #pragma unroll
    for (int i = 0; i < 8; ++i) v[i] = fr[i];
    __syncthreads();
    #pragma unroll
    for (int i = 0; i < 8; ++i) {
      fl[i * 4 + 0][tid] = v[i].x;
      fl[i * 4 + 1][tid] = v[i].y;
      fl[i * 4 + 2][tid] = v[i].z;
      fl[i * 4 + 3][tid] = v[i].w;
    }
    __syncthreads();
    const float* sp = sprjT + ((size_t)b * C_ + cc * 64 + kc * 32) * 36;
    #pragma unroll 4
    for (int k = 0; k < 32; ++k) {
      float f = fl[k][tid];
      const float* sr = sp + k * 36; // uniform -> s_load
      #pragma unroll
      for (int j = 0; j < 36; ++j) acc[j] += f * sr[j];
    }
  }
  float* op = scp + ((size_t)cc * NBLK_ + (size_t)b * 36) * M_ + m0 + tid;
  #pragma unroll
  for (int j = 0; j < 36; ++j) op[(size_t)j * M_] = acc[j];
}

// scg[blk][m] = (sum_cc scp + qbb[blk]) * SCALE. grid = (144, 4), block 256.
// High-parallelism reduce (576 blocks) so topk's read is small + L2-hot.
__global__ __launch_bounds__(256) void score_reduce(const float* __restrict__ scp,
                                                    const float* __restrict__ qbb,
                                                    float* __restrict__ scg) {
  int blk = blockIdx.x;
  int m = blockIdx.y * 1024 + threadIdx.x * 4;
  float qb = qbb[blk];
  float4 s = make_float4(qb, qb, qb, qb);
  #pragma unroll
  for (int cc = 0; cc < 12; ++cc) {
    float4 a = *(const float4*)&scp[((size_t)cc * NBLK_ + blk) * M_ + m];
    s.x += a.x; s.y += a.y; s.z += a.z; s.w += a.w;
  }
  float4 o;
  o.x = s.x * SCALE_;
  o.y = s.y * SCALE_;
  o.z = s.z * SCALE_;
  o.w = s.w * SCALE_;
  *(float4*)&scg[(size_t)blk * M_ + m] = o;
}

// Exact top-K (radix select, index-ordered ties = lax.top_k) + softmax +
// fused bucket scatter. grid = 144, block = 256. Reads L2-resident scg.
__global__ __launch_bounds__(256) void topk_kernel(const float* __restrict__ scg,
                                                   int* __restrict__ ibuf,
                                                   float* __restrict__ wbuf,
                                                   int* __restrict__ bucket) {
  int blk = blockIdx.x;
  int tid = threadIdx.x;

  __shared__ float sc[M_];
  __shared__ unsigned hist[256];
  __shared__ int sbuf[4];
  __shared__ int selm[K_];
  __shared__ float redf[4];
  __shared__ int sh_bin, sh_rem;

  const float4* srow = (const float4*)(scg + (size_t)blk * M_);
  for (int i = tid; i < M_ / 4; i += 256) ((float4*)sc)[i] = srow[i];
  __syncthreads();

  // ---- radix select: find K-th largest key ----
  unsigned prefix = 0;
  int remaining = K_;
  for (int shift = 24; shift >= 0; shift -= 8) {
    hist[tid] = 0;
    __syncthreads();
    unsigned pmask = (shift == 24) ? 0u : (0xFFFFFFFFu << (shift + 8));
    #pragma unroll 4
    for (int i = 0; i < 16; ++i) {
      unsigned k = keyf(sc[tid * 16 + i]);
      if ((k & pmask) == prefix) atomicAdd(&hist[(k >> shift) & 255u], 1u);
    }
    __syncthreads();
    int bin = 255 - tid;
    int v = (int)hist[bin];
    int cex = block_excl_scan256(v, tid, sbuf);
    if (cex < remaining && cex + v >= remaining) {
      sh_bin = bin;
      sh_rem = remaining - cex;
    }
    __syncthreads();
    prefix |= ((unsigned)sh_bin) << shift;
    remaining = sh_rem;
    __syncthreads();
  }
  const unsigned tau = prefix;
  const int r = remaining;      // # of ==tau entries to keep (lowest indices)
  const int cgt = K_ - r;       // # of >tau entries

  // ---- compact selection in ascending-index order (deterministic) ----
  int base = tid * 16;
  int myCnt = 0, myTie = 0;
  #pragma unroll
  for (int i = 0; i < 16; i++) {
    unsigned k = keyf(sc[base + i]);
    myCnt += (k > tau);
    myTie += (k == tau);
  }
  int offs = block_excl_scan256(myCnt, tid, sbuf);
  int toffs = block_excl_scan256(myTie, tid, sbuf);
  for (int i = 0; i < 16; i++) {
    int m = base + i;
    unsigned k = keyf(sc[m]);
    if (k > tau) {
      selm[offs++] = m;
    } else if (k == tau) {
      if (toffs < r) selm[cgt + toffs] = m;
      toffs++;
    }
  }
  __syncthreads();

  // ---- softmax over the K selected (wave reduce + 4-word combine) ----
  int m = selm[tid];
  float val = sc[m];
  float mx = val;
  #pragma unroll
  for (int off = 32; off > 0; off >>= 1) mx = fmaxf(mx, __shfl_xor(mx, off, 64));
  if ((tid & 63) == 0) redf[tid >> 6] = mx;
  __syncthreads();
  mx = fmaxf(fmaxf(redf[0], redf[1]), fmaxf(redf[2], redf[3]));
  float e = expf(val - mx);
  float sm = e;
  #pragma unroll
  for (int off = 32; off > 0; off >>= 1) sm += __shfl_xor(sm, off, 64);
  __syncthreads();
  if ((tid & 63) == 0) redf[tid >> 6] = sm;
  __syncthreads();
  sm = redf[0] + redf[1] + redf[2] + redf[3];
  ibuf[(size_t)blk * K_ + tid] = m;
  wbuf[(size_t)blk * K_ + tid] = e / sm;
  // fused bucket scatter: per (b,m) each th writes at most one slot -> no
  // atomics, deterministic.
  bucket[((size_t)(blk / 36) * M_ + m) * 36 + (blk % 36)] = tid + 1;
}

// wfp[blk*4+kc][c] = sum_{k in chunk} w_k * feat[m_k, c]
// grid = (144, 4, 3 c-segments), block = 256
__global__ __launch_bounds__(256) void wfeat_kernel(const float* __restrict__ x,
                                                    const int* __restrict__ ibuf,
                                                    const float* __restrict__ wbuf,
                                                    float* __restrict__ wfp) {
  int blk = blockIdx.x, kc = blockIdx.y, cseg = blockIdx.z;
  int b = blk / 36;
  int tid = threadIdx.x;
  __shared__ int ml[64];
  __shared__ float wl[64];
  if (tid < 64) {
    ml[tid] = ibuf[(size_t)blk * K_ + kc * 64 + tid];
    wl[tid] = wbuf[(size_t)blk * K_ + kc * 64 + tid];
  }
  __syncthreads();
  int c = cseg * 256 + tid;
  const float* fbase = x + ((size_t)b * TM_ + T_) * C_ + c;
  float a = 0.f;
  #pragma unroll 4
  for (int kk = 0; kk < 64; ++kk) {
    a += wl[kk] * fbase[(size_t)ml[kk] * C_];
  }
  wfp[((size_t)blk * 4 + kc) * C_ + c] = a;
}

// attn_token[b,t,h*64+rr] = (sum_kc wfp) . Wv[row] + bv[row]; grid = 144
__global__ __launch_bounds__(256) void attn_token_kernel(
    const float* __restrict__ wfp, const float* __restrict__ Wkv,
    const float* __restrict__ bkv, float* __restrict__ atbuf) {
  int blk = blockIdx.x;
  int t = blk % T_;
  int h = (blk / T_) % H_;
  int b = blk / (T_ * H_);
  int tid = threadIdx.x;
  __shared__ float wfeat[C_];
  const float* p0 = wfp + ((size_t)blk * 4) * C_;
  #pragma unroll
  for (int j = 0; j < 3; ++j) {
    int c = tid + j * 256;
    wfeat[c] = p0[c] + p0[C_ + c] + p0[2 * C_ + c] + p0[3 * C_ + c];
  }
  __syncthreads();
  int grp = tid >> 4, ln = tid & 15;
  for (int rr = grp; rr < HD_; rr += 16) {
    const float4* wr = (const float4*)(Wkv + ((size_t)(C_ + h * HD_ + rr)) * C_);
    float acc = 0.f;
    #pragma unroll
    for (int it = 0; it < 12; ++it) {
      float4 wv = wr[ln + it * 16];
      const float4 fv = *(const float4*)&wfeat[(ln + it * 16) * 4];
      acc += wv.x * fv.x + wv.y * fv.y + wv.z * fv.z + wv.w * fv.w;
    }
    acc += __shfl_xor(acc, 1, 16);
    acc += __shfl_xor(acc, 2, 16);
    acc += __shfl_xor(acc, 4, 16);
    acc += __shfl_xor(acc, 8, 16);
    if (ln == 0)
      atbuf[((size_t)(b * T_ + t)) * C_ + h * HD_ + rr] =
          acc + bkv[C_ + h * HD_ + rr];
  }
}

// token_output[b,t,d] = sum_c attn_token[b,t,c] * Wexp[t,d,c]
// grid = (T, 12 dchunks of 64), block 256. Fully writes task rows of out.
__global__ __launch_bounds__(256) void token_out(const float* __restrict__ atbuf,
                                                 const float* __restrict__ Wexp,
                                                 float* __restrict__ out) {
  int t = blockIdx.x;
  int d0 = blockIdx.y * 64;
  int tid = threadIdx.x;
  __shared__ float ar[B_][C_];
  for (int i = tid; i < B_ * C_; i += 256) {
    int bb = i / C_, c = i % C_;
    ar[bb][c] = atbuf[((size_t)(bb * T_ + t)) * C_ + c];
  }
  __syncthreads();
  int grp = tid >> 4, ln = tid & 15;
  #pragma unroll
  for (int j = 0; j < 4; ++j) {
    int d = d0 + grp * 4 + j;
    const float4* wr = (const float4*)(Wexp + ((size_t)t * C_ + d) * C_);
    float a0 = 0.f, a1 = 0.f, a2 = 0.f, a3 = 0.f;
    #pragma unroll
    for (int it = 0; it < 12; ++it) {
      float4 w4 = wr[ln + 16 * it];
      const float4 x0 = *(const float4*)&ar[0][(ln + 16 * it) * 4];
      const float4 x1 = *(const float4*)&ar[1][(ln + 16 * it) * 4];
      const float4 x2 = *(const float4*)&ar[2][(ln + 16 * it) * 4];
      const float4 x3 = *(const float4*)&ar[3][(ln + 16 * it) * 4];
      a0 += w4.x * x0.x + w4.y * x0.y + w4.z * x0.z + w4.w * x0.w;
      a1 += w4.x * x1.x + w4.y * x1.y + w4.z * x1.z + w4.w * x1.w;
      a2 += w4.x * x2.x + w4.y * x2.y + w4.z * x2.z + w4.w * x2.w;
      a3 += w4.x * x3.x + w4.y * x3.y + w4.z * x3.z + w4.w * x3.w;
    }
    #pragma unroll
    for (int off = 1; off < 16; off <<= 1) {
      a0 += __shfl_xor(a0, off, 16);
      a1 += __shfl_xor(a1, off, 16);
      a2 += __shfl_xor(a2, off, 16);
      a3 += __shfl_xor(a3, off, 16);
    }
    if (ln == 0) {
      out[((size_t)0 * TM_ + t) * C_ + d] = a0;
      out[((size_t)1 * TM_ + t) * C_ + d] = a1;
      out[((size_t)2 * TM_ + t) * C_ + d] = a2;
      out[((size_t)3 * TM_ + t) * C_ + d] = a3;
    }
  }
}

// All-b MFMA GEMM into dense bf16 Y (no atomics):
//   Y[bht][sel][d] = bf16( w_sel * feat[b,m_sel,h64] @ Wexp[t,:,h64]^T )
// grid = (36 th, 16 = b*4+ks), block = 256 (4 waves); dc looped so fw is
// staged once per block (saves 28MB of re-reads vs grid.z=4).
__global__ __launch_bounds__(256) void scatter_mfma(
    const float* __restrict__ x, const float* __restrict__ Wexp,
    const int* __restrict__ ibuf, const float* __restrict__ wbuf,
    unsigned short* __restrict__ Y) {
  int th = blockIdx.x;
  int h = th / T_, t = th % T_;
  int b = blockIdx.y >> 2, ks = blockIdx.y & 3;
  int bht = b * 36 + th;
  int tid = threadIdx.x;

  __shared__ unsigned short fw[64][72];
  __shared__ unsigned short wt[192][72];

  // stage fw (bf16 of w * feat slice): thread = (kk, 16-c chunk)
  {
    int kk = tid >> 2, cp = (tid & 3) * 16;
    int sel = ks * 64 + kk;
    int m = ibuf[(size_t)bht * K_ + sel];
    float w = wbuf[(size_t)bht * K_ + sel];
    const float* fr = x + ((size_t)(b * TM_) + T_ + m) * C_ + h * HD_ + cp;
    float4 f0 = *(const float4*)(fr + 0);
    float4 f1 = *(const float4*)(fr + 4);
    float4 f2 = *(const float4*)(fr + 8);
    float4 f3 = *(const float4*)(fr + 12);
    uint4 u0 = make_uint4(pk2(f0.x * w, f0.y * w), pk2(f0.z * w, f0.w * w),
                          pk2(f1.x * w, f1.y * w), pk2(f1.z * w, f1.w * w));
    uint4 u1 = make_uint4(pk2(f2.x * w, f2.y * w), pk2(f2.z * w, f2.w * w),
                          pk2(f3.x * w, f3.y * w), pk2(f3.z * w, f3.w * w));
    *(uint4*)&fw[kk][cp] = u0;
    *(uint4*)&fw[kk][cp + 8] = u1;
  }
  __syncthreads();

  int lane = tid & 63, wave = tid >> 6;
  int lrow = lane & 15, lk8 = (lane >> 4) * 8, g4 = (lane >> 4) * 4;

  for (int dc = 0; dc < 4; ++dc) {
    // stage wt[dd][c] = bf16(Wexp[t, dc*192+dd, h*64+c]) — coalesced rows
    {
      #pragma unroll
      for (int r2 = 0; r2 < 3; ++r2) {
        int idx = r2 * 256 + tid;
        int dd = idx >> 2, cq = (idx & 3) * 16;
        const float* wr =
            Wexp + ((size_t)t * C_ + dc * 192 + dd) * C_ + h * HD_ + cq;
        float4 f0 = *(const float4*)(wr + 0);
        float4 f1 = *(const float4*)(wr + 4);
        float4 f2 = *(const float4*)(wr + 8);
        float4 f3 = *(const float4*)(wr + 12);
        uint4 u0 = make_uint4(pk2(f0.x, f0.y), pk2(f0.z, f0.w),
                              pk2(f1.x, f1.y), pk2(f1.z, f1.w));
        uint4 u1 = make_uint4(pk2(f2.x, f2.y), pk2(f2.z, f2.w),
                              pk2(f3.x, f3.y), pk2(f3.z, f3.w));
        *(uint4*)&wt[dd][cq] = u0;
        *(uint4*)&wt[dd][cq + 8] = u1;
      }
    }
    __syncthreads();

    f32x4 acc[12];
    #pragma unroll
    for (int n = 0; n < 12; ++n) acc[n] = (f32x4){0.f, 0.f, 0.f, 0.f};

    #pragma unroll
    for (int ks2 = 0; ks2 < 2; ++ks2) {
      bf16x8 a = *(const bf16x8*)&fw[wave * 16 + lrow][ks2 * 32 + lk8];
      #pragma unroll
      for (int n = 0; n < 12; ++n) {
        bf16x8 bfr = *(const bf16x8*)&wt[n * 16 + lrow][ks2 * 32 + lk8];
        acc[n] = __builtin_amdgcn_mfma_f32_16x16x32_bf16(a, bfr, acc[n], 0, 0, 0);
      }
    }

    // epilogue: D col = lane&15 (d), row = (lane>>4)*4 + q. bf16 stores.
    #pragma unroll
    for (int n = 0; n < 12; ++n) {
      int d = dc * 192 + n * 16 + lrow;
      #pragma unroll
      for (int q = 0; q < 4; ++q) {
        int row = ks * 64 + wave * 16 + g4 + q;
        Y[((size_t)bht * K_ + row) * C_ + d] = f2bf(acc[n][q]);
      }
    }
    __syncthreads(); // all wt reads done before next-dc overwrite
  }
}

// Combine: out[b, T+m, :] = sum over active th (ascending, deterministic) of
// bf16 Y[bht][sel][:]. Rows with no contributions get zeros.
// grid = B*M/4 blocks, block = 256 (wave per (b,m) row).
__global__ __launch_bounds__(256) void combine_kernel(
    const unsigned short* __restrict__ Y, const int* __restrict__ bucket,
    float* __restrict__ out) {
  int wave = threadIdx.x >> 6, lane = threadIdx.x & 63;
  int bm = blockIdx.x * 4 + wave;
  int b = bm / M_, m = bm % M_;
  const int* bk = bucket + (size_t)bm * 36;
  int v = (lane < 36) ? bk[lane] : 0;
  unsigned long long mask = __ballot(v > 0);
  float a[12] = {0.f};
  while (mask) {
    int th = __ffsll((unsigned long long)mask) - 1;
    mask &= mask - 1;
    int sel = __shfl(v, th) - 1;
    const unsigned short* yr = Y + ((size_t)(b * 36 + th) * K_ + sel) * C_;
    #pragma unroll
    for (int seg = 0; seg < 3; ++seg) {
      uint2 r = *(const uint2*)(yr + seg * 256 + lane * 4);
      a[seg * 4 + 0] += bf2f((unsigned short)(r.x & 0xFFFFu));
      a[seg * 4 + 1] += bf2f((unsigned short)(r.x >> 16));
      a[seg * 4 + 2] += bf2f((unsigned short)(r.y & 0xFFFFu));
      a[seg * 4 + 3] += bf2f((unsigned short)(r.y >> 16));
    }
  }
  float* orow = out + ((size_t)b * TM_ + T_ + m) * C_;
  #pragma unroll
  for (int seg = 0; seg < 3; ++seg) {
    float4 o = make_float4(a[seg * 4 + 0], a[seg * 4 + 1], a[seg * 4 + 2],
                           a[seg * 4 + 3]);
    *(float4*)(orow + seg * 256 + lane * 4) = o;
  }
}

// ---------- launch ----------
extern "C" void kernel_launch(void* const* d_in, const int* in_sizes, int n_in,
                              void* d_out, int out_size, void* d_ws, size_t ws_size,
                              hipStream_t stream) {
  (void)in_sizes; (void)n_in; (void)ws_size; (void)out_size;
  const float* x = (const float*)d_in[0];
  const float* Wq = (const float*)d_in[1];
  const float* bq = (const float*)d_in[2];
  const float* Wkv = (const float*)d_in[3];
  const float* bkv = (const float*)d_in[4];
  const float* Wexp = (const float*)d_in[5];
  float* out = (float*)d_out;

  // workspace layout (~64 MiB; scp and Ybf alias — disjoint lifetimes)
  char* ws = (char*)d_ws;
  float* qbuf = (float*)ws;                          //        36,864 B
  float* atbuf = (float*)(ws + 36864);               //        36,864 B
  int* ibuf = (int*)(ws + 73728);                    //       147,456 B
  float* wbuf = (float*)(ws + 221184);               //       147,456 B
  float* sprjT = (float*)(ws + 368640);              //       442,368 B
  float* qbb = (float*)(ws + 811008);                //     1,024 B pad
  float* wfp = (float*)(ws + 812032);                //     1,769,472 B
  int* bucket = (int*)(ws + 2581504);                //     2,359,296 B
  float* scg = (float*)(ws + 4940800);               //     2,359,296 B
  float* scp = (float*)(ws + 7300096);               //    28,311,552 B (12 partials)
  unsigned short* Ybf = (unsigned short*)(ws + 7300096); // 56,623,104 B (alias)
  // end: 63,923,200 B

  q_kernel<<<dim3(T_, 12), 256, 0, stream>>>(x, Wq, bq, qbuf);
  sprj_kernel<<<NBLK_, 256, 0, stream>>>(qbuf, Wkv, bkv, sprjT, qbb,
                                         (uint4*)bucket);
  score_kernel<<<dim3(B_, 16, 12), 256, 0, stream>>>(x, sprjT, scp);
  score_reduce<<<dim3(NBLK_, 4), 256, 0, stream>>>(scp, qbb, scg);
  topk_kernel<<<NBLK_, 256, 0, stream>>>(scg, ibuf, wbuf, bucket);
  wfeat_kernel<<<dim3(NBLK_, 4, 3), 256, 0, stream>>>(x, ibuf, wbuf, wfp);
  attn_token_kernel<<<NBLK_, 256, 0, stream>>>(wfp, Wkv, bkv, atbuf);
  token_out<<<dim3(T_, 12), 256, 0, stream>>>(atbuf, Wexp, out);
  scatter_mfma<<<dim3(36, 16), 256, 0, stream>>>(x, Wexp, ibuf, wbuf, Ybf);
  combine_kernel<<<B_ * M_ / 4, 256, 0, stream>>>(Ybf, bucket, out);
}